// Round 10
// baseline (362.743 us; speedup 1.0000x reference)
//
#include <hip/hip_runtime.h>

typedef unsigned short u16;
typedef unsigned int   u32;
typedef __attribute__((ext_vector_type(8))) short short8;
typedef __attribute__((ext_vector_type(4))) short short4_t;
typedef __attribute__((ext_vector_type(4))) float f32x4;

__device__ __forceinline__ float bf2f(u16 v) {
  return __uint_as_float(((u32)v) << 16);
}
__device__ __forceinline__ u16 f2bf(float f) {
  u32 u = __float_as_uint(f);
  u32 r = (u + 0x7FFFu + ((u >> 16) & 1u)) >> 16;   // RNE
  return (u16)r;
}
// NaN-propagating ReLU (fmaxf(NaN,0)=0 would hide poison as zeros)
__device__ __forceinline__ float relu(float x) { return x < 0.f ? 0.f : x; }

// async global->LDS, 16B/lane; LDS dest = wave-uniform base + lane*16
__device__ __forceinline__ void gld16(const void* g, void* l) {
  __builtin_amdgcn_global_load_lds((const __attribute__((address_space(1))) u32*)g,
                                   (__attribute__((address_space(3))) u32*)l, 16, 0, 0);
}

// ---------------------------------------------------------------------------
// 1a. partial column sums of frame batch 0; block (0,0) also zeroes
//     raw1/raw2/raw3 + bar (1024 floats total) — replaces hipMemsetAsync.
//     (bar is consumed only by norm3f, many stream-ordered dispatches later.)
__global__ void colmean_part_kernel(const float* __restrict__ frame,
                                    double* __restrict__ partD,
                                    float* __restrict__ rawZ) {
  if (blockIdx.x == 0 && blockIdx.y == 0) {
    rawZ[threadIdx.x] = 0.f;
    rawZ[threadIdx.x + 256] = 0.f;
    rawZ[threadIdx.x + 512] = 0.f;
    rawZ[threadIdx.x + 768] = 0.f;      // includes bar (int 0 == f32 0.0 bits)
  }
  int tf = blockIdx.x * 256 + threadIdx.x;           // 4096
  int ch = blockIdx.y;                               // 8 chunks
  const float* f0 = frame + tf + (size_t)ch * 64 * 4096;
  double s = 0.0;
  for (int c = 0; c < 64; ++c) s += (double)f0[(size_t)c * 4096];
  partD[ch * 4096 + tf] = s;
}

// ---------------------------------------------------------------------------
// 2. f64: mean = (in-order chunk combine)/512; S = sum; q = mean/S; cumsum;
//    cdf = min(int(c*2048), 2047).
__global__ void scanD_kernel(const double* __restrict__ partD, int* __restrict__ cdf) {
  __shared__ double part[256];
  __shared__ double base[256];
  __shared__ double Ss;
  int tid = threadIdx.x;
  double loc[16];
  double s = 0.0;
#pragma unroll
  for (int i = 0; i < 16; ++i) {
    int tf = tid * 16 + i;
    double m = 0.0;
#pragma unroll
    for (int ch = 0; ch < 8; ++ch) m += partD[ch * 4096 + tf];  // in c-order
    loc[i] = m / 512.0;
    s += loc[i];
  }
  part[tid] = s;
  __syncthreads();
  if (tid == 0) {
    double t = 0.0;
    for (int i = 0; i < 256; ++i) t += part[i];
    Ss = t;
  }
  __syncthreads();
  double S = Ss;
  s = 0.0;
#pragma unroll
  for (int i = 0; i < 16; ++i) { loc[i] = loc[i] / S; s += loc[i]; }
  part[tid] = s;
  __syncthreads();
  if (tid == 0) {
    double c = 0.0;
    for (int i = 0; i < 256; ++i) { base[i] = c; c += part[i]; }
  }
  __syncthreads();
  double c = base[tid];
#pragma unroll
  for (int i = 0; i < 16; ++i) {
    c += loc[i];
    int iv = (int)(c * 2048.0);                      // trunc = astype(int32)
    cdf[tid * 16 + i] = iv < 2047 ? iv : 2047;
  }
}

// ---------------------------------------------------------------------------
// 3. idx[target] = first argmin_j |cdf[j]-target|
__global__ void argmin_kernel(const int* __restrict__ cdf, int* __restrict__ idx) {
  __shared__ int sd[256], sj[256];
  int target = blockIdx.x;                            // 2048 blocks
  int tid = threadIdx.x;
  int best = 0x7fffffff, bj = 0x7fffffff;
  for (int j = tid; j < 4096; j += 256) {
    int d = cdf[j] - target; d = d < 0 ? -d : d;
    if (d < best) { best = d; bj = j; }               // strict < keeps first
  }
  sd[tid] = best; sj[tid] = bj;
  __syncthreads();
  for (int s = 128; s > 0; s >>= 1) {
    if (tid < s) {
      if (sd[tid+s] < sd[tid] || (sd[tid+s] == sd[tid] && sj[tid+s] < sj[tid])) {
        sd[tid] = sd[tid+s]; sj[tid] = sj[tid+s];
      }
    }
    __syncthreads();
  }
  if (tid == 0) idx[target] = sj[0];
}

// ---------------------------------------------------------------------------
// 4+5+6a merged. z<4: gather X3T; z<8: transpose featT; z>=8: convW12
//   (768 flat blocks, 1 float4/thread — independent work, fills the grid).
__global__ void gatherTrans_kernel(const float* __restrict__ frame,
                                   const float* __restrict__ feature,
                                   const int* __restrict__ idx,
                                   const float* __restrict__ W1,
                                   const float* __restrict__ W2,
                                   u16* __restrict__ X3T, u16* __restrict__ featT,
                                   u16* __restrict__ W12b) {
  __shared__ u16 tile[64][65];
  __shared__ int sidx[64];
  int tid = threadIdx.x;
  int zz = blockIdx.z;
  if (zz >= 8) {                        // weight conversion slice
    int flat = (zz - 8) * 256 + blockIdx.y * 8 + blockIdx.x;   // [0,768)
    int i = (flat * 256 + tid) * 4;
    f32x4 v = *(const f32x4*)(i < 262144 ? W1 + i : W2 + (i - 262144));
    short4_t o;
#pragma unroll
    for (int e = 0; e < 4; ++e) o[e] = (short)f2bf(v[e]);
    *(short4_t*)(W12b + i) = o;
    return;
  }
  int cb = blockIdx.x * 64, t0 = blockIdx.y * 64;
  int b = zz & 3, which = zz >> 2;
  if (which == 0) {
    if (tid < 64) {
      int it = idx[t0 + tid];
      sidx[tid] = it < 0 ? 0 : (it > 4095 ? 4095 : it);
    }
    __syncthreads();
    const float* fb = frame + (size_t)b * 512 * 4096;
    for (int i = tid; i < 4096; i += 256) {
      int r = i >> 6, tt = i & 63;        // r = c-local, tt = t-local
      tile[tt][r] = f2bf(fb[(size_t)(cb + r) * 4096 + sidx[tt]]);
    }
    __syncthreads();
    u16* xb = X3T + (size_t)b * 2048 * 2048;
    for (int i = tid; i < 4096; i += 256) {
      int r = i >> 6, cc = i & 63;        // r = t-local, cc = c-local
      xb[(size_t)(t0 + r) * 2048 + cb + cc] = tile[r][cc];
    }
  } else {
    const float* xb = feature + (size_t)b * 512 * 2048;
    for (int i = tid; i < 4096; i += 256) {
      int r = i >> 6, tt = i & 63;        // coalesced along t
      tile[tt][r] = f2bf(xb[(size_t)(cb + r) * 2048 + t0 + tt]);
    }
    __syncthreads();
    u16* xtb = featT + (size_t)b * 2048 * 512;
    for (int i = tid; i < 4096; i += 256) {
      int r = i >> 6, cc = i & 63;
      xtb[(size_t)(t0 + r) * 512 + cb + cc] = tile[r][cc];
    }
  }
}

// ---------------------------------------------------------------------------
// 6b. W3 conversion (must run after normT12: W3b aliases dead Y12f rows)
__global__ void convW_kernel(const float* __restrict__ src, u16* __restrict__ dst) {
  int i = (blockIdx.x * 256 + threadIdx.x) * 4;      // 1048576 total, grid 1024
  f32x4 v = *(const f32x4*)(src + i);
  short4_t o;
#pragma unroll
  for (int e = 0; e < 4; ++e) o[e] = (short)f2bf(v[e]);
  *(short4_t*)(dst + i) = o;
}

// ---------------------------------------------------------------------------
// 7a. fused GEMM1+2 (r2/r7/r8-verified): Y12 + bias; GN1/GN2 stats fused.
//     M=1536, N=2048, K=512. 64x128 tile, 2 waves. Conflict-free both-sides
//     16B-slot XOR swizzle. 1536 blocks -> 6/CU resident.
__global__ __launch_bounds__(128) void gemm12_kernel(
    const u16* __restrict__ A, const u16* __restrict__ Bt,
    const float* __restrict__ b1, const float* __restrict__ b2,
    float* __restrict__ Y, float* __restrict__ raw1, float* __restrict__ raw2)
{
  const int K = 512;
  __shared__ short As[2][2048];   // [buf][64 m][32 k]
  __shared__ short Bs[2][4096];   // [buf][128 n][32 k]
  const int tid = threadIdx.x;
  const int lane = tid & 63;
  const int w = tid >> 6;
  const int nt = blockIdx.x, mt = blockIdx.y, bb = blockIdx.z;
  const u16* Ab = A + (size_t)mt * 64 * K;
  const u16* Bb = Bt + ((size_t)bb * 2048 + (size_t)nt * 128) * K;
  const int lm = lane & 15, lq = lane >> 4;
  f32x4 acc[4][4] = {};

  auto stage = [&](int buf, int kt) {
#pragma unroll
    for (int p = 0; p < 2; ++p) {
      int chunk = tid + 128 * p;
      int row = chunk >> 2;
      int ko = ((chunk & 3) ^ ((row >> 1) & 3)) << 3;   // source pre-swizzle
      gld16(Ab + (size_t)row * K + kt + ko, (char*)As[buf] + chunk * 16);
    }
#pragma unroll
    for (int p = 0; p < 4; ++p) {
      int chunk = tid + 128 * p;
      int row = chunk >> 2;
      int ko = ((chunk & 3) ^ ((row >> 1) & 3)) << 3;
      gld16(Bb + (size_t)row * K + kt + ko, (char*)Bs[buf] + chunk * 16);
    }
  };

  stage(0, 0);
  for (int s = 0; s < 16; ++s) {
    int cur = s & 1;
    __syncthreads();
    if (s + 1 < 16) stage(cur ^ 1, (s + 1) << 5);
    short8 af[4], bfv[4];
#pragma unroll
    for (int i = 0; i < 4; ++i) {
      int r = i * 16 + lm;
      af[i] = *(const short8*)(As[cur] + r * 32 + ((lq ^ ((r >> 1) & 3)) << 3));
    }
#pragma unroll
    for (int j = 0; j < 4; ++j) {
      int r = w * 64 + j * 16 + lm;
      bfv[j] = *(const short8*)(Bs[cur] + r * 32 + ((lq ^ ((r >> 1) & 3)) << 3));
    }
#pragma unroll
    for (int i = 0; i < 4; ++i)
#pragma unroll
      for (int j = 0; j < 4; ++j)
        acc[i][j] = __builtin_amdgcn_mfma_f32_16x16x32_bf16(af[i], bfv[j], acc[i][j], 0, 0, 0);
  }

  float s1[4] = {0.f, 0.f, 0.f, 0.f};
  float s2[4] = {0.f, 0.f, 0.f, 0.f};
#pragma unroll
  for (int i = 0; i < 4; ++i) {
    int mbase = mt * 64 + i * 16 + lq * 4;
#pragma unroll
    for (int e = 0; e < 4; ++e) {
      int m = mbase + e;
      float bv = m < 512 ? b1[m] : b2[m - 512];
      float* yp = Y + ((size_t)bb * 1536 + m) * 2048 + nt * 128 + w * 64 + lm;
#pragma unroll
      for (int j = 0; j < 4; ++j) {
        float v = acc[i][j][e] + bv;
        yp[j * 16] = v;
        s1[i] += v; s2[i] += v * v;
      }
    }
  }
#pragma unroll
  for (int i = 0; i < 4; ++i) {
#pragma unroll
    for (int off = 32; off > 0; off >>= 1) {
      s1[i] += __shfl_xor(s1[i], off);
      s2[i] += __shfl_xor(s2[i], off);
    }
  }
  if (lane == 0) {
    if (mt < 8) {                                  // GN1: cpg=16, frag = 1 group
#pragma unroll
      for (int i = 0; i < 4; ++i) {
        int g = mt * 4 + i;
        atomicAdd(&raw1[(bb * 32 + g) * 2],     s1[i]);
        atomicAdd(&raw1[(bb * 32 + g) * 2 + 1], s2[i]);
      }
    } else {                                       // GN2: cpg=32, 2 frags = 1 group
#pragma unroll
      for (int i = 0; i < 2; ++i) {
        int g = (mt - 8) * 2 + i;
        atomicAdd(&raw2[(bb * 32 + g) * 2],     s1[2 * i] + s1[2 * i + 1]);
        atomicAdd(&raw2[(bb * 32 + g) * 2 + 1], s2[2 * i] + s2[2 * i + 1]);
      }
    }
  }
}

// ---------------------------------------------------------------------------
// 7b. GEMM3 split-K x2 (r2/r7/r8-verified). M=512, N=2048, K=2048. 64x128
//     tile, 2 waves, grid.z = b*2+ks -> 1024 blocks. Conflict-free swizzle.
//     Fusion post-mortems r5/r6/r9: this latency-bound 2-phase loop needs
//     many independent small blocks; every coupling variant lost >=30us.
__global__ __launch_bounds__(128) void gemm3s_kernel(
    const u16* __restrict__ A, const u16* __restrict__ Bt,
    const float* __restrict__ bias, float* __restrict__ Yp)
{
  const int K = 2048;
  __shared__ short As[2][2048];
  __shared__ short Bs[2][4096];
  const int tid = threadIdx.x;
  const int lane = tid & 63;
  const int w = tid >> 6;
  const int nt = blockIdx.x, mt = blockIdx.y;
  const int bb = blockIdx.z >> 1, ks = blockIdx.z & 1;
  const u16* Ab = A + (size_t)mt * 64 * K + ks * 1024;
  const u16* Bb = Bt + ((size_t)bb * 2048 + (size_t)nt * 128) * K + ks * 1024;
  const int lm = lane & 15, lq = lane >> 4;
  f32x4 acc[4][4] = {};

  auto stage = [&](int buf, int kt) {
#pragma unroll
    for (int p = 0; p < 2; ++p) {
      int chunk = tid + 128 * p;
      int row = chunk >> 2;
      int ko = ((chunk & 3) ^ ((row >> 1) & 3)) << 3;
      gld16(Ab + (size_t)row * K + kt + ko, (char*)As[buf] + chunk * 16);
    }
#pragma unroll
    for (int p = 0; p < 4; ++p) {
      int chunk = tid + 128 * p;
      int row = chunk >> 2;
      int ko = ((chunk & 3) ^ ((row >> 1) & 3)) << 3;
      gld16(Bb + (size_t)row * K + kt + ko, (char*)Bs[buf] + chunk * 16);
    }
  };

  stage(0, 0);
  for (int s = 0; s < 32; ++s) {
    int cur = s & 1;
    __syncthreads();
    if (s + 1 < 32) stage(cur ^ 1, (s + 1) << 5);
    short8 af[4], bfv[4];
#pragma unroll
    for (int i = 0; i < 4; ++i) {
      int r = i * 16 + lm;
      af[i] = *(const short8*)(As[cur] + r * 32 + ((lq ^ ((r >> 1) & 3)) << 3));
    }
#pragma unroll
    for (int j = 0; j < 4; ++j) {
      int r = w * 64 + j * 16 + lm;
      bfv[j] = *(const short8*)(Bs[cur] + r * 32 + ((lq ^ ((r >> 1) & 3)) << 3));
    }
#pragma unroll
    for (int i = 0; i < 4; ++i)
#pragma unroll
      for (int j = 0; j < 4; ++j)
        acc[i][j] = __builtin_amdgcn_mfma_f32_16x16x32_bf16(af[i], bfv[j], acc[i][j], 0, 0, 0);
  }
#pragma unroll
  for (int i = 0; i < 4; ++i) {
    int mbase = mt * 64 + i * 16 + lq * 4;
#pragma unroll
    for (int e = 0; e < 4; ++e) {
      int m = mbase + e;
      float bv = ks ? 0.f : bias[m];
      float* yp = Yp + ((size_t)(ks * 4 + bb) * 512 + m) * 2048 + nt * 128 + w * 64 + lm;
#pragma unroll
      for (int j = 0; j < 4; ++j)
        yp[j * 16] = acc[i][j][e] + bv;
    }
  }
}

// ---------------------------------------------------------------------------
// 9. normT1+normT2 merged (r8-verified). grid.y=24: y<8 -> GN1, y>=8 -> GN2.
__global__ void normT12_kernel(const float* __restrict__ Y,
                               const float* __restrict__ raw1,
                               const float* __restrict__ raw2,
                               const float* __restrict__ g1, const float* __restrict__ be1,
                               const float* __restrict__ g2, const float* __restrict__ be2,
                               u16* __restrict__ X3T, float* __restrict__ featOut) {
  __shared__ u16 tile[64][65];           // [t_local][c_local]
  int b = blockIdx.z, t0 = blockIdx.x * 64;
  int yb_idx = blockIdx.y;
  const int gn2 = yb_idx >= 8;
  int c0 = (gn2 ? yb_idx - 8 : yb_idx) * 64;
  const float* raw   = gn2 ? raw2 : raw1;
  const float* gamma = gn2 ? g2 : g1;
  const float* beta  = gn2 ? be2 : be1;
  const float inv_n  = gn2 ? (1.f / 65536.f) : (1.f / 32768.f);
  const int chBase   = gn2 ? 512 : 0;
  const int gShift   = gn2 ? 5 : 4;
  const int colBase  = gn2 ? 512 : 1536;
  const float* yb = Y + ((size_t)b * 1536 + chBase) * 2048;
  for (int i = threadIdx.x; i < 4096; i += 256) {
    int r = i >> 6, cc = i & 63;         // r: channel-local, cc: t-local
    int ch = c0 + r;
    int gI = (b * 32 + (ch >> gShift)) * 2;
    float mu = raw[gI] * inv_n;
    float var = raw[gI + 1] * inv_n - mu * mu;
    float rs = 1.0f / sqrtf(var + 1e-5f);
    float v = yb[(size_t)ch * 2048 + t0 + cc];
    float o = relu((v - mu) * rs * gamma[ch] + beta[ch]);
    tile[cc][r] = f2bf(o);
    if (gn2) featOut[((size_t)b * 1024 + ch) * 2048 + t0 + cc] = o;
  }
  __syncthreads();
  for (int i = threadIdx.x; i < 4096; i += 256) {
    int r = i >> 6, cc = i & 63;         // r: t-local, cc: c-local
    X3T[((size_t)b * 2048 + t0 + r) * 2048 + colBase + c0 + cc] = tile[r][cc];
  }
}

// ---------------------------------------------------------------------------
// 10. FUSED stats3p+norm3 via grid barrier (streaming op, no LDS pipeline:
//     1024 blocks x 4 waves, 2x residency slack -> barrier = phase skew only).
//     Block = 2 consecutive channels of one batch (one GN group). Read Y3p
//     pair ONCE into registers, stats -> atomics -> barrier -> normalize from
//     registers -> write outMixed. Deletes the 33MB re-read + 1 dispatch.
__global__ __launch_bounds__(256) void norm3f_kernel(
    const float* __restrict__ Yp,
    const float* __restrict__ gamma, const float* __restrict__ beta,
    float* __restrict__ raw3, int* __restrict__ bar,
    float* __restrict__ out)
{
  const int tid = threadIdx.x;
  const int blk = blockIdx.x;            // 1024
  const int b = blk >> 8;
  const int ch0 = (blk & 255) * 2;       // two consecutive channels, same group
  const int g = ch0 >> 4;
  const size_t base4 = (size_t)blk * 1024;          // f4 units
  const f32x4* yp4 = (const f32x4*)Yp;

  // k<2 -> row ch0, k>=2 -> row ch0+1 (tid+256k spans the block's 1024 f4s)
  f32x4 v[4];
  float s = 0.f, ss = 0.f;
#pragma unroll
  for (int k = 0; k < 4; ++k) {
    size_t i4 = base4 + tid + 256 * k;
    f32x4 a = yp4[i4];
    f32x4 c = yp4[i4 + 1048576];
#pragma unroll
    for (int e = 0; e < 4; ++e) {
      float x = a[e] + c[e];
      v[k][e] = x;
      s += x; ss += x * x;
    }
  }
  __shared__ float s1[256], s2[256];
  __shared__ float stat[2];
  s1[tid] = s; s2[tid] = ss;
  __syncthreads();
  for (int st = 128; st > 0; st >>= 1) {
    if (tid < st) { s1[tid] += s1[tid + st]; s2[tid] += s2[tid + st]; }
    __syncthreads();
  }
  if (tid == 0) {
    atomicAdd(&raw3[(b * 32 + g) * 2],     s1[0]);
    atomicAdd(&raw3[(b * 32 + g) * 2 + 1], s2[0]);
    __threadfence();
    __hip_atomic_fetch_add(bar, 1, __ATOMIC_RELEASE, __HIP_MEMORY_SCOPE_AGENT);
    while (__hip_atomic_load(bar, __ATOMIC_ACQUIRE, __HIP_MEMORY_SCOPE_AGENT) < 1024) {
      __builtin_amdgcn_s_sleep(8);
    }
    float sA = __hip_atomic_load(&raw3[(b * 32 + g) * 2],     __ATOMIC_RELAXED,
                                 __HIP_MEMORY_SCOPE_AGENT);
    float sB = __hip_atomic_load(&raw3[(b * 32 + g) * 2 + 1], __ATOMIC_RELAXED,
                                 __HIP_MEMORY_SCOPE_AGENT);
    float mu = sA * (1.f / 32768.f);
    stat[0] = mu;
    stat[1] = 1.0f / sqrtf(sB * (1.f / 32768.f) - mu * mu + 1e-5f);
  }
  __syncthreads();
  const float mu = stat[0], rs = stat[1];
  const float ga0 = gamma[ch0], bt0 = beta[ch0];
  const float ga1 = gamma[ch0 + 1], bt1 = beta[ch0 + 1];
  f32x4* out4 = (f32x4*)out;
#pragma unroll
  for (int k = 0; k < 4; ++k) {
    float ga = k < 2 ? ga0 : ga1;
    float bt = k < 2 ? bt0 : bt1;
    f32x4 o;
#pragma unroll
    for (int e = 0; e < 4; ++e)
      o[e] = relu((v[k][e] - mu) * rs * ga + bt);
    out4[base4 + tid + 256 * k] = o;
  }
}

// ---------------------------------------------------------------------------
extern "C" void kernel_launch(void* const* d_in, const int* in_sizes, int n_in,
                              void* d_out, int out_size, void* d_ws, size_t ws_size,
                              hipStream_t stream) {
  const float* feature = (const float*)d_in[0];
  const float* frame   = (const float*)d_in[1];
  const float* W1 = (const float*)d_in[2];
  const float* b1 = (const float*)d_in[3];
  const float* g1 = (const float*)d_in[4];
  const float* be1 = (const float*)d_in[5];
  const float* W2 = (const float*)d_in[6];
  const float* b2 = (const float*)d_in[7];
  const float* g2 = (const float*)d_in[8];
  const float* be2 = (const float*)d_in[9];
  const float* W3 = (const float*)d_in[10];
  const float* b3 = (const float*)d_in[11];
  const float* g3 = (const float*)d_in[12];
  const float* be3 = (const float*)d_in[13];

  char* ws = (char*)d_ws;
  // Layout / stream-ordered aliasing (r2/r7/r8-verified):
  //   X3T   [0, 32MiB)            bf16 (B,2048t,2048c)
  //   Y12f  [32MiB, 80MiB)        f32 (B,1536,2048) = GEMM1+2 output
  //   Y3p   [32MiB, 64MiB)        f32 split-K partial pair (after normT12)
  //   W3b   [64MiB, 66MiB)        bf16, written after normT12 (Y12 dead)
  //   partD [48MiB, +256KiB)      f64, dead before gemm12 writes Y12
  //   featT [80MiB, 88MiB)        bf16 (B,2048,512)
  //   W12b  [88MiB, +1.5MiB)      bf16 stacked W1;W2
  //   small tail after W12b (cdf/idx/raw1/raw2/raw3/bar)
  u16*    X3T   = (u16*)(ws + 0);
  float*  Y12f  = (float*)(ws + 33554432);
  float*  Y3p   = (float*)(ws + 33554432);
  u16*    W3b   = (u16*)(ws + 67108864);
  double* partD = (double*)(ws + 50331648);
  u16*    featT = (u16*)(ws + 83886080);
  u16*    W12b  = (u16*)(ws + 92274688);
  int*    cdf   = (int*)(ws + 93847552);
  int*    idx   = (int*)(ws + 93863936);
  float*  raw1  = (float*)(ws + 93872128);
  float*  raw2  = (float*)(ws + 93873152);
  float*  raw3  = (float*)(ws + 93874176);
  int*    bar   = (int*)(ws + 93875200);

  float* outMixed = (float*)d_out;                       // (B,512,2048) fp32
  float* outFeat  = outMixed + (size_t)4 * 512 * 2048;   // (B,1024,2048) fp32

  colmean_part_kernel<<<dim3(16, 8), 256, 0, stream>>>(frame, partD, raw1);
  scanD_kernel<<<1, 256, 0, stream>>>(partD, cdf);
  argmin_kernel<<<2048, 256, 0, stream>>>(cdf, idx);
  gatherTrans_kernel<<<dim3(8, 32, 11), 256, 0, stream>>>(frame, feature, idx,
                                                          W1, W2, X3T, featT, W12b);
  gemm12_kernel<<<dim3(16, 24, 4), 128, 0, stream>>>(W12b, featT, b1, b2, Y12f,
                                                     raw1, raw2);
  normT12_kernel<<<dim3(32, 24, 4), 256, 0, stream>>>(Y12f, raw1, raw2,
                                                      g1, be1, g2, be2,
                                                      X3T, outFeat);
  convW_kernel<<<1024, 256, 0, stream>>>(W3, W3b);
  gemm3s_kernel<<<dim3(16, 8, 8), 128, 0, stream>>>(W3b, X3T, b3, Y3p);
  norm3f_kernel<<<1024, 256, 0, stream>>>(Y3p, g3, be3, raw3, bar, outMixed);
}

// Round 11
// 258.373 us; speedup vs baseline: 1.4040x; 1.4040x over previous
//
#include <hip/hip_runtime.h>

typedef unsigned short u16;
typedef unsigned int   u32;
typedef __attribute__((ext_vector_type(8))) short short8;
typedef __attribute__((ext_vector_type(4))) short short4_t;
typedef __attribute__((ext_vector_type(4))) float f32x4;

__device__ __forceinline__ float bf2f(u16 v) {
  return __uint_as_float(((u32)v) << 16);
}
__device__ __forceinline__ u16 f2bf(float f) {
  u32 u = __float_as_uint(f);
  u32 r = (u + 0x7FFFu + ((u >> 16) & 1u)) >> 16;   // RNE
  return (u16)r;
}
// NaN-propagating ReLU (fmaxf(NaN,0)=0 would hide poison as zeros)
__device__ __forceinline__ float relu(float x) { return x < 0.f ? 0.f : x; }

// async global->LDS, 16B/lane; LDS dest = wave-uniform base + lane*16
__device__ __forceinline__ void gld16(const void* g, void* l) {
  __builtin_amdgcn_global_load_lds((const __attribute__((address_space(1))) u32*)g,
                                   (__attribute__((address_space(3))) u32*)l, 16, 0, 0);
}

// ---------------------------------------------------------------------------
// 1a. partial column sums of frame batch 0; block (0,0) also zeroes
//     raw1/raw2/raw3 (768 floats) — replaces hipMemsetAsync.
__global__ void colmean_part_kernel(const float* __restrict__ frame,
                                    double* __restrict__ partD,
                                    float* __restrict__ rawZ) {
  if (blockIdx.x == 0 && blockIdx.y == 0) {
    rawZ[threadIdx.x] = 0.f;
    rawZ[threadIdx.x + 256] = 0.f;
    rawZ[threadIdx.x + 512] = 0.f;
  }
  int tf = blockIdx.x * 256 + threadIdx.x;           // 4096
  int ch = blockIdx.y;                               // 8 chunks
  const float* f0 = frame + tf + (size_t)ch * 64 * 4096;
  double s = 0.0;
  for (int c = 0; c < 64; ++c) s += (double)f0[(size_t)c * 4096];
  partD[ch * 4096 + tf] = s;
}

// ---------------------------------------------------------------------------
// 2. f64: mean = (in-order chunk combine)/512; S = sum; q = mean/S; cumsum;
//    cdf = min(int(c*2048), 2047).
__global__ void scanD_kernel(const double* __restrict__ partD, int* __restrict__ cdf) {
  __shared__ double part[256];
  __shared__ double base[256];
  __shared__ double Ss;
  int tid = threadIdx.x;
  double loc[16];
  double s = 0.0;
#pragma unroll
  for (int i = 0; i < 16; ++i) {
    int tf = tid * 16 + i;
    double m = 0.0;
#pragma unroll
    for (int ch = 0; ch < 8; ++ch) m += partD[ch * 4096 + tf];  // in c-order
    loc[i] = m / 512.0;
    s += loc[i];
  }
  part[tid] = s;
  __syncthreads();
  if (tid == 0) {
    double t = 0.0;
    for (int i = 0; i < 256; ++i) t += part[i];
    Ss = t;
  }
  __syncthreads();
  double S = Ss;
  s = 0.0;
#pragma unroll
  for (int i = 0; i < 16; ++i) { loc[i] = loc[i] / S; s += loc[i]; }
  part[tid] = s;
  __syncthreads();
  if (tid == 0) {
    double c = 0.0;
    for (int i = 0; i < 256; ++i) { base[i] = c; c += part[i]; }
  }
  __syncthreads();
  double c = base[tid];
#pragma unroll
  for (int i = 0; i < 16; ++i) {
    c += loc[i];
    int iv = (int)(c * 2048.0);                      // trunc = astype(int32)
    cdf[tid * 16 + i] = iv < 2047 ? iv : 2047;
  }
}

// ---------------------------------------------------------------------------
// first argmin_j |cdf[j]-t| for MONOTONE non-decreasing cdf (cumsum of
// strictly-positive means): candidates are v1 = largest value <= t and
// v2 = smallest value >= t; first index achieving the min distance is the
// head of the winning value's plateau (ties -> v1's head, the earlier one).
__device__ __forceinline__ int lowbound(const int* __restrict__ cdf, int hi0, int v) {
  int lo = 0, hi = hi0;
  while (lo < hi) { int mid = (lo + hi) >> 1; if (cdf[mid] < v) lo = mid + 1; else hi = mid; }
  return lo;
}
__device__ __forceinline__ int argmin_cdf(const int* __restrict__ cdf, int t) {
  int j2 = lowbound(cdf, 4096, t);       // first index with cdf >= t
  if (j2 == 0) return 0;                 // plateau head of v2 is j2 itself
  if (j2 == 4096) return lowbound(cdf, 4096, cdf[4095]);
  int d2 = cdf[j2] - t, d1 = t - cdf[j2 - 1];
  if (d2 < d1) return j2;                // j2 is first index with value v2
  return lowbound(cdf, j2, cdf[j2 - 1]); // head of v1 plateau (d1<=d2 -> earlier)
}

// ---------------------------------------------------------------------------
// 4+5+6a merged (r10-verified) + argmin folded in (binary search, no idx buf).
//   z<4: gather X3T[b][t][c] = bf16(frame[b][c][idx[t]]), c in [0,512)
//   z<8: transpose featT[b][t][c] = bf16(feature[b][c][t])
//   z>=8: convW12 (768 flat blocks, 1 float4/thread)
__global__ void gatherTrans_kernel(const float* __restrict__ frame,
                                   const float* __restrict__ feature,
                                   const int* __restrict__ cdf,
                                   const float* __restrict__ W1,
                                   const float* __restrict__ W2,
                                   u16* __restrict__ X3T, u16* __restrict__ featT,
                                   u16* __restrict__ W12b) {
  __shared__ u16 tile[64][65];
  __shared__ int sidx[64];
  int tid = threadIdx.x;
  int zz = blockIdx.z;
  if (zz >= 8) {                        // weight conversion slice
    int flat = (zz - 8) * 256 + blockIdx.y * 8 + blockIdx.x;   // [0,768)
    int i = (flat * 256 + tid) * 4;
    f32x4 v = *(const f32x4*)(i < 262144 ? W1 + i : W2 + (i - 262144));
    short4_t o;
#pragma unroll
    for (int e = 0; e < 4; ++e) o[e] = (short)f2bf(v[e]);
    *(short4_t*)(W12b + i) = o;
    return;
  }
  int cb = blockIdx.x * 64, t0 = blockIdx.y * 64;
  int b = zz & 3, which = zz >> 2;
  if (which == 0) {
    if (tid < 64) sidx[tid] = argmin_cdf(cdf, t0 + tid);   // in [0,4095]
    __syncthreads();
    const float* fb = frame + (size_t)b * 512 * 4096;
    for (int i = tid; i < 4096; i += 256) {
      int r = i >> 6, tt = i & 63;        // r = c-local, tt = t-local
      tile[tt][r] = f2bf(fb[(size_t)(cb + r) * 4096 + sidx[tt]]);
    }
    __syncthreads();
    u16* xb = X3T + (size_t)b * 2048 * 2048;
    for (int i = tid; i < 4096; i += 256) {
      int r = i >> 6, cc = i & 63;        // r = t-local, cc = c-local
      xb[(size_t)(t0 + r) * 2048 + cb + cc] = tile[r][cc];
    }
  } else {
    const float* xb = feature + (size_t)b * 512 * 2048;
    for (int i = tid; i < 4096; i += 256) {
      int r = i >> 6, tt = i & 63;        // coalesced along t
      tile[tt][r] = f2bf(xb[(size_t)(cb + r) * 2048 + t0 + tt]);
    }
    __syncthreads();
    u16* xtb = featT + (size_t)b * 2048 * 512;
    for (int i = tid; i < 4096; i += 256) {
      int r = i >> 6, cc = i & 63;
      xtb[(size_t)(t0 + r) * 512 + cb + cc] = tile[r][cc];
    }
  }
}

// ---------------------------------------------------------------------------
// 6b. W3 conversion (must run after normT12: W3b aliases dead Y12f rows)
__global__ void convW_kernel(const float* __restrict__ src, u16* __restrict__ dst) {
  int i = (blockIdx.x * 256 + threadIdx.x) * 4;      // 1048576 total, grid 1024
  f32x4 v = *(const f32x4*)(src + i);
  short4_t o;
#pragma unroll
  for (int e = 0; e < 4; ++e) o[e] = (short)f2bf(v[e]);
  *(short4_t*)(dst + i) = o;
}

// ---------------------------------------------------------------------------
// 7a. fused GEMM1+2 (r2/r7/r8-verified): Y12 + bias; GN1/GN2 stats fused.
//     M=1536, N=2048, K=512. 64x128 tile, 2 waves. Conflict-free both-sides
//     16B-slot XOR swizzle. 1536 blocks -> 6/CU resident.
__global__ __launch_bounds__(128) void gemm12_kernel(
    const u16* __restrict__ A, const u16* __restrict__ Bt,
    const float* __restrict__ b1, const float* __restrict__ b2,
    float* __restrict__ Y, float* __restrict__ raw1, float* __restrict__ raw2)
{
  const int K = 512;
  __shared__ short As[2][2048];   // [buf][64 m][32 k]
  __shared__ short Bs[2][4096];   // [buf][128 n][32 k]
  const int tid = threadIdx.x;
  const int lane = tid & 63;
  const int w = tid >> 6;
  const int nt = blockIdx.x, mt = blockIdx.y, bb = blockIdx.z;
  const u16* Ab = A + (size_t)mt * 64 * K;
  const u16* Bb = Bt + ((size_t)bb * 2048 + (size_t)nt * 128) * K;
  const int lm = lane & 15, lq = lane >> 4;
  f32x4 acc[4][4] = {};

  auto stage = [&](int buf, int kt) {
#pragma unroll
    for (int p = 0; p < 2; ++p) {
      int chunk = tid + 128 * p;
      int row = chunk >> 2;
      int ko = ((chunk & 3) ^ ((row >> 1) & 3)) << 3;   // source pre-swizzle
      gld16(Ab + (size_t)row * K + kt + ko, (char*)As[buf] + chunk * 16);
    }
#pragma unroll
    for (int p = 0; p < 4; ++p) {
      int chunk = tid + 128 * p;
      int row = chunk >> 2;
      int ko = ((chunk & 3) ^ ((row >> 1) & 3)) << 3;
      gld16(Bb + (size_t)row * K + kt + ko, (char*)Bs[buf] + chunk * 16);
    }
  };

  stage(0, 0);
  for (int s = 0; s < 16; ++s) {
    int cur = s & 1;
    __syncthreads();
    if (s + 1 < 16) stage(cur ^ 1, (s + 1) << 5);
    short8 af[4], bfv[4];
#pragma unroll
    for (int i = 0; i < 4; ++i) {
      int r = i * 16 + lm;
      af[i] = *(const short8*)(As[cur] + r * 32 + ((lq ^ ((r >> 1) & 3)) << 3));
    }
#pragma unroll
    for (int j = 0; j < 4; ++j) {
      int r = w * 64 + j * 16 + lm;
      bfv[j] = *(const short8*)(Bs[cur] + r * 32 + ((lq ^ ((r >> 1) & 3)) << 3));
    }
#pragma unroll
    for (int i = 0; i < 4; ++i)
#pragma unroll
      for (int j = 0; j < 4; ++j)
        acc[i][j] = __builtin_amdgcn_mfma_f32_16x16x32_bf16(af[i], bfv[j], acc[i][j], 0, 0, 0);
  }

  float s1[4] = {0.f, 0.f, 0.f, 0.f};
  float s2[4] = {0.f, 0.f, 0.f, 0.f};
#pragma unroll
  for (int i = 0; i < 4; ++i) {
    int mbase = mt * 64 + i * 16 + lq * 4;
#pragma unroll
    for (int e = 0; e < 4; ++e) {
      int m = mbase + e;
      float bv = m < 512 ? b1[m] : b2[m - 512];
      float* yp = Y + ((size_t)bb * 1536 + m) * 2048 + nt * 128 + w * 64 + lm;
#pragma unroll
      for (int j = 0; j < 4; ++j) {
        float v = acc[i][j][e] + bv;
        yp[j * 16] = v;
        s1[i] += v; s2[i] += v * v;
      }
    }
  }
#pragma unroll
  for (int i = 0; i < 4; ++i) {
#pragma unroll
    for (int off = 32; off > 0; off >>= 1) {
      s1[i] += __shfl_xor(s1[i], off);
      s2[i] += __shfl_xor(s2[i], off);
    }
  }
  if (lane == 0) {
    if (mt < 8) {                                  // GN1: cpg=16, frag = 1 group
#pragma unroll
      for (int i = 0; i < 4; ++i) {
        int g = mt * 4 + i;
        atomicAdd(&raw1[(bb * 32 + g) * 2],     s1[i]);
        atomicAdd(&raw1[(bb * 32 + g) * 2 + 1], s2[i]);
      }
    } else {                                       // GN2: cpg=32, 2 frags = 1 group
#pragma unroll
      for (int i = 0; i < 2; ++i) {
        int g = (mt - 8) * 2 + i;
        atomicAdd(&raw2[(bb * 32 + g) * 2],     s1[2 * i] + s1[2 * i + 1]);
        atomicAdd(&raw2[(bb * 32 + g) * 2 + 1], s2[2 * i] + s2[2 * i + 1]);
      }
    }
  }
}

// ---------------------------------------------------------------------------
// 7b. GEMM3 split-K x2 (r2/r7/r8-verified). M=512, N=2048, K=2048. 64x128
//     tile, 2 waves, grid.z = b*2+ks -> 1024 blocks. Conflict-free swizzle.
//     Fusion post-mortems r5/r6/r9/r10: latency-bound 2-phase GEMM needs many
//     independent small blocks; grid barriers cost ~(arrivals x 100ns). Chain.
__global__ __launch_bounds__(128) void gemm3s_kernel(
    const u16* __restrict__ A, const u16* __restrict__ Bt,
    const float* __restrict__ bias, float* __restrict__ Yp)
{
  const int K = 2048;
  __shared__ short As[2][2048];
  __shared__ short Bs[2][4096];
  const int tid = threadIdx.x;
  const int lane = tid & 63;
  const int w = tid >> 6;
  const int nt = blockIdx.x, mt = blockIdx.y;
  const int bb = blockIdx.z >> 1, ks = blockIdx.z & 1;
  const u16* Ab = A + (size_t)mt * 64 * K + ks * 1024;
  const u16* Bb = Bt + ((size_t)bb * 2048 + (size_t)nt * 128) * K + ks * 1024;
  const int lm = lane & 15, lq = lane >> 4;
  f32x4 acc[4][4] = {};

  auto stage = [&](int buf, int kt) {
#pragma unroll
    for (int p = 0; p < 2; ++p) {
      int chunk = tid + 128 * p;
      int row = chunk >> 2;
      int ko = ((chunk & 3) ^ ((row >> 1) & 3)) << 3;
      gld16(Ab + (size_t)row * K + kt + ko, (char*)As[buf] + chunk * 16);
    }
#pragma unroll
    for (int p = 0; p < 4; ++p) {
      int chunk = tid + 128 * p;
      int row = chunk >> 2;
      int ko = ((chunk & 3) ^ ((row >> 1) & 3)) << 3;
      gld16(Bb + (size_t)row * K + kt + ko, (char*)Bs[buf] + chunk * 16);
    }
  };

  stage(0, 0);
  for (int s = 0; s < 32; ++s) {
    int cur = s & 1;
    __syncthreads();
    if (s + 1 < 32) stage(cur ^ 1, (s + 1) << 5);
    short8 af[4], bfv[4];
#pragma unroll
    for (int i = 0; i < 4; ++i) {
      int r = i * 16 + lm;
      af[i] = *(const short8*)(As[cur] + r * 32 + ((lq ^ ((r >> 1) & 3)) << 3));
    }
#pragma unroll
    for (int j = 0; j < 4; ++j) {
      int r = w * 64 + j * 16 + lm;
      bfv[j] = *(const short8*)(Bs[cur] + r * 32 + ((lq ^ ((r >> 1) & 3)) << 3));
    }
#pragma unroll
    for (int i = 0; i < 4; ++i)
#pragma unroll
      for (int j = 0; j < 4; ++j)
        acc[i][j] = __builtin_amdgcn_mfma_f32_16x16x32_bf16(af[i], bfv[j], acc[i][j], 0, 0, 0);
  }
#pragma unroll
  for (int i = 0; i < 4; ++i) {
    int mbase = mt * 64 + i * 16 + lq * 4;
#pragma unroll
    for (int e = 0; e < 4; ++e) {
      int m = mbase + e;
      float bv = ks ? 0.f : bias[m];
      float* yp = Yp + ((size_t)(ks * 4 + bb) * 512 + m) * 2048 + nt * 128 + w * 64 + lm;
#pragma unroll
      for (int j = 0; j < 4; ++j)
        yp[j * 16] = acc[i][j][e] + bv;
    }
  }
}

// ---------------------------------------------------------------------------
// 8b. stage-1 for split-K Y3: reads partial pair, float4-vectorized (r7/r8)
__global__ void stats3p_kernel(const float* __restrict__ Yp, float* __restrict__ raw) {
  int chunk = blockIdx.x, g = blockIdx.y, b = blockIdx.z, tid = threadIdx.x;
  const f32x4* base = (const f32x4*)(Yp + ((size_t)b * 512 + g * 16) * 2048
                                        + (size_t)chunk * 4096);
  float s = 0.f, ss = 0.f;
#pragma unroll
  for (int i = 0; i < 4; ++i) {
    f32x4 a = base[tid + 256 * i];
    f32x4 c = base[tid + 256 * i + 1048576];    // +4194304 floats
#pragma unroll
    for (int e = 0; e < 4; ++e) {
      float v = a[e] + c[e];
      s += v; ss += v * v;
    }
  }
  __shared__ float s1[256], s2[256];
  s1[tid] = s; s2[tid] = ss;
  __syncthreads();
  for (int st = 128; st > 0; st >>= 1) {
    if (tid < st) { s1[tid] += s1[tid + st]; s2[tid] += s2[tid + st]; }
    __syncthreads();
  }
  if (tid == 0) {
    atomicAdd(&raw[(b * 32 + g) * 2],     s1[0]);
    atomicAdd(&raw[(b * 32 + g) * 2 + 1], s2[0]);
  }
}

// ---------------------------------------------------------------------------
// 9. normT1+normT2 merged (r8-verified). grid.y=24: y<8 -> GN1, y>=8 -> GN2.
__global__ void normT12_kernel(const float* __restrict__ Y,
                               const float* __restrict__ raw1,
                               const float* __restrict__ raw2,
                               const float* __restrict__ g1, const float* __restrict__ be1,
                               const float* __restrict__ g2, const float* __restrict__ be2,
                               u16* __restrict__ X3T, float* __restrict__ featOut) {
  __shared__ u16 tile[64][65];           // [t_local][c_local]
  int b = blockIdx.z, t0 = blockIdx.x * 64;
  int yb_idx = blockIdx.y;
  const int gn2 = yb_idx >= 8;
  int c0 = (gn2 ? yb_idx - 8 : yb_idx) * 64;
  const float* raw   = gn2 ? raw2 : raw1;
  const float* gamma = gn2 ? g2 : g1;
  const float* beta  = gn2 ? be2 : be1;
  const float inv_n  = gn2 ? (1.f / 65536.f) : (1.f / 32768.f);
  const int chBase   = gn2 ? 512 : 0;
  const int gShift   = gn2 ? 5 : 4;
  const int colBase  = gn2 ? 512 : 1536;
  const float* yb = Y + ((size_t)b * 1536 + chBase) * 2048;
  for (int i = threadIdx.x; i < 4096; i += 256) {
    int r = i >> 6, cc = i & 63;         // r: channel-local, cc: t-local
    int ch = c0 + r;
    int gI = (b * 32 + (ch >> gShift)) * 2;
    float mu = raw[gI] * inv_n;
    float var = raw[gI + 1] * inv_n - mu * mu;
    float rs = 1.0f / sqrtf(var + 1e-5f);
    float v = yb[(size_t)ch * 2048 + t0 + cc];
    float o = relu((v - mu) * rs * gamma[ch] + beta[ch]);
    tile[cc][r] = f2bf(o);
    if (gn2) featOut[((size_t)b * 1024 + ch) * 2048 + t0 + cc] = o;
  }
  __syncthreads();
  for (int i = threadIdx.x; i < 4096; i += 256) {
    int r = i >> 6, cc = i & 63;         // r: t-local, cc: c-local
    X3T[((size_t)b * 2048 + t0 + r) * 2048 + colBase + c0 + cc] = tile[r][cc];
  }
}

// ---------------------------------------------------------------------------
// 10. GN+ReLU for split-K Y3 partial pair -> fp32 mixed output.
//     float4-vectorized; statsFin folded (r7/r8-verified).
__global__ void norm3_kernel(const float* __restrict__ Yp, const float* __restrict__ raw,
                             const float* __restrict__ gamma, const float* __restrict__ beta,
                             float* __restrict__ out) {
  int i4 = blockIdx.x * 256 + threadIdx.x;           // 1,048,576 float4s
  int b = i4 >> 18;                                  // 262144 f4 per batch
  int ch = (i4 >> 9) & 511;                          // 512 f4 per channel row
  int gI = (b * 32 + (ch >> 4)) * 2;
  float mu = raw[gI] * (1.f / 32768.f);
  float var = raw[gI + 1] * (1.f / 32768.f) - mu * mu;
  float rs = 1.0f / sqrtf(var + 1e-5f);
  float ga = gamma[ch], bt = beta[ch];
  f32x4 a = ((const f32x4*)Yp)[i4];
  f32x4 c = ((const f32x4*)Yp)[i4 + 1048576];
  f32x4 o;
#pragma unroll
  for (int e = 0; e < 4; ++e)
    o[e] = relu((a[e] + c[e] - mu) * rs * ga + bt);
  ((f32x4*)out)[i4] = o;
}

// ---------------------------------------------------------------------------
extern "C" void kernel_launch(void* const* d_in, const int* in_sizes, int n_in,
                              void* d_out, int out_size, void* d_ws, size_t ws_size,
                              hipStream_t stream) {
  const float* feature = (const float*)d_in[0];
  const float* frame   = (const float*)d_in[1];
  const float* W1 = (const float*)d_in[2];
  const float* b1 = (const float*)d_in[3];
  const float* g1 = (const float*)d_in[4];
  const float* be1 = (const float*)d_in[5];
  const float* W2 = (const float*)d_in[6];
  const float* b2 = (const float*)d_in[7];
  const float* g2 = (const float*)d_in[8];
  const float* be2 = (const float*)d_in[9];
  const float* W3 = (const float*)d_in[10];
  const float* b3 = (const float*)d_in[11];
  const float* g3 = (const float*)d_in[12];
  const float* be3 = (const float*)d_in[13];

  char* ws = (char*)d_ws;
  // Layout / stream-ordered aliasing (r2/r7/r8-verified):
  //   X3T   [0, 32MiB)            bf16 (B,2048t,2048c)
  //   Y12f  [32MiB, 80MiB)        f32 (B,1536,2048) = GEMM1+2 output
  //   Y3p   [32MiB, 64MiB)        f32 split-K partial pair (after normT12)
  //   W3b   [64MiB, 66MiB)        bf16, written after normT12 (Y12 dead)
  //   partD [48MiB, +256KiB)      f64, dead before gemm12 writes Y12
  //   featT [80MiB, 88MiB)        bf16 (B,2048,512)
  //   W12b  [88MiB, +1.5MiB)      bf16 stacked W1;W2
  //   small tail after W12b (cdf/raw1/raw2/raw3)
  u16*    X3T   = (u16*)(ws + 0);
  float*  Y12f  = (float*)(ws + 33554432);
  float*  Y3p   = (float*)(ws + 33554432);
  u16*    W3b   = (u16*)(ws + 67108864);
  double* partD = (double*)(ws + 50331648);
  u16*    featT = (u16*)(ws + 83886080);
  u16*    W12b  = (u16*)(ws + 92274688);
  int*    cdf   = (int*)(ws + 93847552);
  float*  raw1  = (float*)(ws + 93872128);
  float*  raw2  = (float*)(ws + 93873152);
  float*  raw3  = (float*)(ws + 93874176);

  float* outMixed = (float*)d_out;                       // (B,512,2048) fp32
  float* outFeat  = outMixed + (size_t)4 * 512 * 2048;   // (B,1024,2048) fp32

  colmean_part_kernel<<<dim3(16, 8), 256, 0, stream>>>(frame, partD, raw1);
  scanD_kernel<<<1, 256, 0, stream>>>(partD, cdf);
  gatherTrans_kernel<<<dim3(8, 32, 11), 256, 0, stream>>>(frame, feature, cdf,
                                                          W1, W2, X3T, featT, W12b);
  gemm12_kernel<<<dim3(16, 24, 4), 128, 0, stream>>>(W12b, featT, b1, b2, Y12f,
                                                     raw1, raw2);
  normT12_kernel<<<dim3(32, 24, 4), 256, 0, stream>>>(Y12f, raw1, raw2,
                                                      g1, be1, g2, be2,
                                                      X3T, outFeat);
  convW_kernel<<<1024, 256, 0, stream>>>(W3, W3b);
  gemm3s_kernel<<<dim3(16, 8, 8), 128, 0, stream>>>(W3b, X3T, b3, Y3p);
  stats3p_kernel<<<dim3(8, 32, 4), 256, 0, stream>>>(Y3p, raw3);
  norm3_kernel<<<4096, 256, 0, stream>>>(Y3p, raw3, g3, be3, outMixed);
}

// Round 12
// 258.034 us; speedup vs baseline: 1.4058x; 1.0013x over previous
//
#include <hip/hip_runtime.h>

typedef unsigned short u16;
typedef unsigned int   u32;
typedef __attribute__((ext_vector_type(8))) short short8;
typedef __attribute__((ext_vector_type(4))) short short4_t;
typedef __attribute__((ext_vector_type(4))) float f32x4;

__device__ __forceinline__ float bf2f(u16 v) {
  return __uint_as_float(((u32)v) << 16);
}
__device__ __forceinline__ u16 f2bf(float f) {
  u32 u = __float_as_uint(f);
  u32 r = (u + 0x7FFFu + ((u >> 16) & 1u)) >> 16;   // RNE
  return (u16)r;
}
// NaN-propagating ReLU (fmaxf(NaN,0)=0 would hide poison as zeros)
__device__ __forceinline__ float relu(float x) { return x < 0.f ? 0.f : x; }

// async global->LDS, 16B/lane; LDS dest = wave-uniform base + lane*16
__device__ __forceinline__ void gld16(const void* g, void* l) {
  __builtin_amdgcn_global_load_lds((const __attribute__((address_space(1))) u32*)g,
                                   (__attribute__((address_space(3))) u32*)l, 16, 0, 0);
}

// ---------------------------------------------------------------------------
// 1a. partial column sums of frame batch 0; block (0,0) also zeroes
//     raw1/raw2 (512 floats) — replaces hipMemsetAsync.
__global__ void colmean_part_kernel(const float* __restrict__ frame,
                                    double* __restrict__ partD,
                                    float* __restrict__ rawZ) {
  if (blockIdx.x == 0 && blockIdx.y == 0) {
    rawZ[threadIdx.x] = 0.f;
    rawZ[threadIdx.x + 256] = 0.f;
  }
  int tf = blockIdx.x * 256 + threadIdx.x;           // 4096
  int ch = blockIdx.y;                               // 8 chunks
  const float* f0 = frame + tf + (size_t)ch * 64 * 4096;
  double s = 0.0;
  for (int c = 0; c < 64; ++c) s += (double)f0[(size_t)c * 4096];
  partD[ch * 4096 + tf] = s;
}

// ---------------------------------------------------------------------------
// 2. f64: mean = (in-order chunk combine)/512; S = sum; q = mean/S; cumsum;
//    cdf = min(int(c*2048), 2047).
__global__ void scanD_kernel(const double* __restrict__ partD, int* __restrict__ cdf) {
  __shared__ double part[256];
  __shared__ double base[256];
  __shared__ double Ss;
  int tid = threadIdx.x;
  double loc[16];
  double s = 0.0;
#pragma unroll
  for (int i = 0; i < 16; ++i) {
    int tf = tid * 16 + i;
    double m = 0.0;
#pragma unroll
    for (int ch = 0; ch < 8; ++ch) m += partD[ch * 4096 + tf];  // in c-order
    loc[i] = m / 512.0;
    s += loc[i];
  }
  part[tid] = s;
  __syncthreads();
  if (tid == 0) {
    double t = 0.0;
    for (int i = 0; i < 256; ++i) t += part[i];
    Ss = t;
  }
  __syncthreads();
  double S = Ss;
  s = 0.0;
#pragma unroll
  for (int i = 0; i < 16; ++i) { loc[i] = loc[i] / S; s += loc[i]; }
  part[tid] = s;
  __syncthreads();
  if (tid == 0) {
    double c = 0.0;
    for (int i = 0; i < 256; ++i) { base[i] = c; c += part[i]; }
  }
  __syncthreads();
  double c = base[tid];
#pragma unroll
  for (int i = 0; i < 16; ++i) {
    c += loc[i];
    int iv = (int)(c * 2048.0);                      // trunc = astype(int32)
    cdf[tid * 16 + i] = iv < 2047 ? iv : 2047;
  }
}

// ---------------------------------------------------------------------------
// first argmin_j |cdf[j]-t| for MONOTONE non-decreasing cdf (r11-verified).
__device__ __forceinline__ int lowbound(const int* __restrict__ cdf, int hi0, int v) {
  int lo = 0, hi = hi0;
  while (lo < hi) { int mid = (lo + hi) >> 1; if (cdf[mid] < v) lo = mid + 1; else hi = mid; }
  return lo;
}
__device__ __forceinline__ int argmin_cdf(const int* __restrict__ cdf, int t) {
  int j2 = lowbound(cdf, 4096, t);       // first index with cdf >= t
  if (j2 == 0) return 0;                 // plateau head of v2 is j2 itself
  if (j2 == 4096) return lowbound(cdf, 4096, cdf[4095]);
  int d2 = cdf[j2] - t, d1 = t - cdf[j2 - 1];
  if (d2 < d1) return j2;                // j2 is first index with value v2
  return lowbound(cdf, j2, cdf[j2 - 1]); // head of v1 plateau (d1<=d2 -> earlier)
}

// ---------------------------------------------------------------------------
// 4+5+6a merged (r10/r11-verified) + inline argmin.
//   z<4: gather X3T; z<8: transpose featT; z>=8: convW12
__global__ void gatherTrans_kernel(const float* __restrict__ frame,
                                   const float* __restrict__ feature,
                                   const int* __restrict__ cdf,
                                   const float* __restrict__ W1,
                                   const float* __restrict__ W2,
                                   u16* __restrict__ X3T, u16* __restrict__ featT,
                                   u16* __restrict__ W12b) {
  __shared__ u16 tile[64][65];
  __shared__ int sidx[64];
  int tid = threadIdx.x;
  int zz = blockIdx.z;
  if (zz >= 8) {                        // weight conversion slice
    int flat = (zz - 8) * 256 + blockIdx.y * 8 + blockIdx.x;   // [0,768)
    int i = (flat * 256 + tid) * 4;
    f32x4 v = *(const f32x4*)(i < 262144 ? W1 + i : W2 + (i - 262144));
    short4_t o;
#pragma unroll
    for (int e = 0; e < 4; ++e) o[e] = (short)f2bf(v[e]);
    *(short4_t*)(W12b + i) = o;
    return;
  }
  int cb = blockIdx.x * 64, t0 = blockIdx.y * 64;
  int b = zz & 3, which = zz >> 2;
  if (which == 0) {
    if (tid < 64) sidx[tid] = argmin_cdf(cdf, t0 + tid);   // in [0,4095]
    __syncthreads();
    const float* fb = frame + (size_t)b * 512 * 4096;
    for (int i = tid; i < 4096; i += 256) {
      int r = i >> 6, tt = i & 63;        // r = c-local, tt = t-local
      tile[tt][r] = f2bf(fb[(size_t)(cb + r) * 4096 + sidx[tt]]);
    }
    __syncthreads();
    u16* xb = X3T + (size_t)b * 2048 * 2048;
    for (int i = tid; i < 4096; i += 256) {
      int r = i >> 6, cc = i & 63;        // r = t-local, cc = c-local
      xb[(size_t)(t0 + r) * 2048 + cb + cc] = tile[r][cc];
    }
  } else {
    const float* xb = feature + (size_t)b * 512 * 2048;
    for (int i = tid; i < 4096; i += 256) {
      int r = i >> 6, tt = i & 63;        // coalesced along t
      tile[tt][r] = f2bf(xb[(size_t)(cb + r) * 2048 + t0 + tt]);
    }
    __syncthreads();
    u16* xtb = featT + (size_t)b * 2048 * 512;
    for (int i = tid; i < 4096; i += 256) {
      int r = i >> 6, cc = i & 63;
      xtb[(size_t)(t0 + r) * 512 + cb + cc] = tile[r][cc];
    }
  }
}

// ---------------------------------------------------------------------------
// 7a. fused GEMM1+2 (r2/r7/r8-verified): Y12 + bias; GN1/GN2 stats fused.
//     M=1536, N=2048, K=512. 64x128 tile, 2 waves. Conflict-free both-sides
//     16B-slot XOR swizzle. 1536 blocks -> 6/CU resident.
__global__ __launch_bounds__(128) void gemm12_kernel(
    const u16* __restrict__ A, const u16* __restrict__ Bt,
    const float* __restrict__ b1, const float* __restrict__ b2,
    float* __restrict__ Y, float* __restrict__ raw1, float* __restrict__ raw2)
{
  const int K = 512;
  __shared__ short As[2][2048];   // [buf][64 m][32 k]
  __shared__ short Bs[2][4096];   // [buf][128 n][32 k]
  const int tid = threadIdx.x;
  const int lane = tid & 63;
  const int w = tid >> 6;
  const int nt = blockIdx.x, mt = blockIdx.y, bb = blockIdx.z;
  const u16* Ab = A + (size_t)mt * 64 * K;
  const u16* Bb = Bt + ((size_t)bb * 2048 + (size_t)nt * 128) * K;
  const int lm = lane & 15, lq = lane >> 4;
  f32x4 acc[4][4] = {};

  auto stage = [&](int buf, int kt) {
#pragma unroll
    for (int p = 0; p < 2; ++p) {
      int chunk = tid + 128 * p;
      int row = chunk >> 2;
      int ko = ((chunk & 3) ^ ((row >> 1) & 3)) << 3;   // source pre-swizzle
      gld16(Ab + (size_t)row * K + kt + ko, (char*)As[buf] + chunk * 16);
    }
#pragma unroll
    for (int p = 0; p < 4; ++p) {
      int chunk = tid + 128 * p;
      int row = chunk >> 2;
      int ko = ((chunk & 3) ^ ((row >> 1) & 3)) << 3;
      gld16(Bb + (size_t)row * K + kt + ko, (char*)Bs[buf] + chunk * 16);
    }
  };

  stage(0, 0);
  for (int s = 0; s < 16; ++s) {
    int cur = s & 1;
    __syncthreads();
    if (s + 1 < 16) stage(cur ^ 1, (s + 1) << 5);
    short8 af[4], bfv[4];
#pragma unroll
    for (int i = 0; i < 4; ++i) {
      int r = i * 16 + lm;
      af[i] = *(const short8*)(As[cur] + r * 32 + ((lq ^ ((r >> 1) & 3)) << 3));
    }
#pragma unroll
    for (int j = 0; j < 4; ++j) {
      int r = w * 64 + j * 16 + lm;
      bfv[j] = *(const short8*)(Bs[cur] + r * 32 + ((lq ^ ((r >> 1) & 3)) << 3));
    }
#pragma unroll
    for (int i = 0; i < 4; ++i)
#pragma unroll
      for (int j = 0; j < 4; ++j)
        acc[i][j] = __builtin_amdgcn_mfma_f32_16x16x32_bf16(af[i], bfv[j], acc[i][j], 0, 0, 0);
  }

  float s1[4] = {0.f, 0.f, 0.f, 0.f};
  float s2[4] = {0.f, 0.f, 0.f, 0.f};
#pragma unroll
  for (int i = 0; i < 4; ++i) {
    int mbase = mt * 64 + i * 16 + lq * 4;
#pragma unroll
    for (int e = 0; e < 4; ++e) {
      int m = mbase + e;
      float bv = m < 512 ? b1[m] : b2[m - 512];
      float* yp = Y + ((size_t)bb * 1536 + m) * 2048 + nt * 128 + w * 64 + lm;
#pragma unroll
      for (int j = 0; j < 4; ++j) {
        float v = acc[i][j][e] + bv;
        yp[j * 16] = v;
        s1[i] += v; s2[i] += v * v;
      }
    }
  }
#pragma unroll
  for (int i = 0; i < 4; ++i) {
#pragma unroll
    for (int off = 32; off > 0; off >>= 1) {
      s1[i] += __shfl_xor(s1[i], off);
      s2[i] += __shfl_xor(s2[i], off);
    }
  }
  if (lane == 0) {
    if (mt < 8) {                                  // GN1: cpg=16, frag = 1 group
#pragma unroll
      for (int i = 0; i < 4; ++i) {
        int g = mt * 4 + i;
        atomicAdd(&raw1[(bb * 32 + g) * 2],     s1[i]);
        atomicAdd(&raw1[(bb * 32 + g) * 2 + 1], s2[i]);
      }
    } else {                                       // GN2: cpg=32, 2 frags = 1 group
#pragma unroll
      for (int i = 0; i < 2; ++i) {
        int g = (mt - 8) * 2 + i;
        atomicAdd(&raw2[(bb * 32 + g) * 2],     s1[2 * i] + s1[2 * i + 1]);
        atomicAdd(&raw2[(bb * 32 + g) * 2 + 1], s2[2 * i] + s2[2 * i + 1]);
      }
    }
  }
}

// ---------------------------------------------------------------------------
// 7b. GEMM3 split-K x2 (r2/r7/r8-verified). M=512, N=2048, K=2048. 64x128
//     tile, 2 waves, grid.z = b*2+ks -> 1024 blocks. Conflict-free swizzle.
//     Fusion post-mortems r5/r6/r9/r10: latency-bound 2-phase GEMM needs many
//     independent small blocks; grid barriers cost ~(arrivals x 100ns). Chain.
__global__ __launch_bounds__(128) void gemm3s_kernel(
    const u16* __restrict__ A, const u16* __restrict__ Bt,
    const float* __restrict__ bias, float* __restrict__ Yp)
{
  const int K = 2048;
  __shared__ short As[2][2048];
  __shared__ short Bs[2][4096];
  const int tid = threadIdx.x;
  const int lane = tid & 63;
  const int w = tid >> 6;
  const int nt = blockIdx.x, mt = blockIdx.y;
  const int bb = blockIdx.z >> 1, ks = blockIdx.z & 1;
  const u16* Ab = A + (size_t)mt * 64 * K + ks * 1024;
  const u16* Bb = Bt + ((size_t)bb * 2048 + (size_t)nt * 128) * K + ks * 1024;
  const int lm = lane & 15, lq = lane >> 4;
  f32x4 acc[4][4] = {};

  auto stage = [&](int buf, int kt) {
#pragma unroll
    for (int p = 0; p < 2; ++p) {
      int chunk = tid + 128 * p;
      int row = chunk >> 2;
      int ko = ((chunk & 3) ^ ((row >> 1) & 3)) << 3;
      gld16(Ab + (size_t)row * K + kt + ko, (char*)As[buf] + chunk * 16);
    }
#pragma unroll
    for (int p = 0; p < 4; ++p) {
      int chunk = tid + 128 * p;
      int row = chunk >> 2;
      int ko = ((chunk & 3) ^ ((row >> 1) & 3)) << 3;
      gld16(Bb + (size_t)row * K + kt + ko, (char*)Bs[buf] + chunk * 16);
    }
  };

  stage(0, 0);
  for (int s = 0; s < 32; ++s) {
    int cur = s & 1;
    __syncthreads();
    if (s + 1 < 32) stage(cur ^ 1, (s + 1) << 5);
    short8 af[4], bfv[4];
#pragma unroll
    for (int i = 0; i < 4; ++i) {
      int r = i * 16 + lm;
      af[i] = *(const short8*)(As[cur] + r * 32 + ((lq ^ ((r >> 1) & 3)) << 3));
    }
#pragma unroll
    for (int j = 0; j < 4; ++j) {
      int r = w * 64 + j * 16 + lm;
      bfv[j] = *(const short8*)(Bs[cur] + r * 32 + ((lq ^ ((r >> 1) & 3)) << 3));
    }
#pragma unroll
    for (int i = 0; i < 4; ++i)
#pragma unroll
      for (int j = 0; j < 4; ++j)
        acc[i][j] = __builtin_amdgcn_mfma_f32_16x16x32_bf16(af[i], bfv[j], acc[i][j], 0, 0, 0);
  }
#pragma unroll
  for (int i = 0; i < 4; ++i) {
    int mbase = mt * 64 + i * 16 + lq * 4;
#pragma unroll
    for (int e = 0; e < 4; ++e) {
      int m = mbase + e;
      float bv = ks ? 0.f : bias[m];
      float* yp = Yp + ((size_t)(ks * 4 + bb) * 512 + m) * 2048 + nt * 128 + w * 64 + lm;
#pragma unroll
      for (int j = 0; j < 4; ++j)
        yp[j * 16] = acc[i][j][e] + bv;
    }
  }
}

// ---------------------------------------------------------------------------
// 9. normT1+normT2 merged (r8-verified) + convW(W3) folded as y==24 slice
//    (W3b lives in the dead featT region; featT is dead once gemm12 is done,
//    and this kernel runs strictly after gemm12).
__global__ void normT12_kernel(const float* __restrict__ Y,
                               const float* __restrict__ raw1,
                               const float* __restrict__ raw2,
                               const float* __restrict__ g1, const float* __restrict__ be1,
                               const float* __restrict__ g2, const float* __restrict__ be2,
                               const float* __restrict__ W3, u16* __restrict__ W3b,
                               u16* __restrict__ X3T, float* __restrict__ featOut) {
  __shared__ u16 tile[64][65];           // [t_local][c_local]
  int b = blockIdx.z, t0 = blockIdx.x * 64;
  int yb_idx = blockIdx.y;
  if (yb_idx == 24) {                    // W3 -> bf16 slice: 128 blocks
    int flat = blockIdx.z * 32 + blockIdx.x;            // [0,128)
#pragma unroll
    for (int k = 0; k < 8; ++k) {
      int i = (flat * 2048 + k * 256 + threadIdx.x) * 4;  // 1048576 u16 total
      f32x4 v = *(const f32x4*)(W3 + i);
      short4_t o;
#pragma unroll
      for (int e = 0; e < 4; ++e) o[e] = (short)f2bf(v[e]);
      *(short4_t*)(W3b + i) = o;
    }
    return;
  }
  const int gn2 = yb_idx >= 8;
  int c0 = (gn2 ? yb_idx - 8 : yb_idx) * 64;
  const float* raw   = gn2 ? raw2 : raw1;
  const float* gamma = gn2 ? g2 : g1;
  const float* beta  = gn2 ? be2 : be1;
  const float inv_n  = gn2 ? (1.f / 65536.f) : (1.f / 32768.f);
  const int chBase   = gn2 ? 512 : 0;
  const int gShift   = gn2 ? 5 : 4;
  const int colBase  = gn2 ? 512 : 1536;
  const float* yb = Y + ((size_t)b * 1536 + chBase) * 2048;
  for (int i = threadIdx.x; i < 4096; i += 256) {
    int r = i >> 6, cc = i & 63;         // r: channel-local, cc: t-local
    int ch = c0 + r;
    int gI = (b * 32 + (ch >> gShift)) * 2;
    float mu = raw[gI] * inv_n;
    float var = raw[gI + 1] * inv_n - mu * mu;
    float rs = 1.0f / sqrtf(var + 1e-5f);
    float v = yb[(size_t)ch * 2048 + t0 + cc];
    float o = relu((v - mu) * rs * gamma[ch] + beta[ch]);
    tile[cc][r] = f2bf(o);
    if (gn2) featOut[((size_t)b * 1024 + ch) * 2048 + t0 + cc] = o;
  }
  __syncthreads();
  for (int i = threadIdx.x; i < 4096; i += 256) {
    int r = i >> 6, cc = i & 63;         // r: t-local, cc: c-local
    X3T[((size_t)b * 2048 + t0 + r) * 2048 + colBase + c0 + cc] = tile[r][cc];
  }
}

// ---------------------------------------------------------------------------
// 10. MERGED stats+GN+ReLU for split-K Y3: one block per (batch, group).
//     128 blocks x 1024 threads; the whole 16ch x 2048t group pair is read
//     ONCE into registers (v[8] f32x4 = 32 VGPR), stats via plain intra-block
//     reduce (no atomics / no grid sync), normalize from registers, write.
//     Replaces stats3p + norm3: -32MB HBM, -1 dispatch, no raw3 buffer.
__global__ __launch_bounds__(1024) void norm3g_kernel(
    const float* __restrict__ Yp,
    const float* __restrict__ gamma, const float* __restrict__ beta,
    float* __restrict__ out)
{
  const int tid = threadIdx.x;          // 1024
  const int g = blockIdx.x;             // 32 groups
  const int b = blockIdx.y;             // 4 batches
  const f32x4* a4 = (const f32x4*)(Yp + ((size_t)b * 512 + g * 16) * 2048);
  const f32x4* c4 = a4 + 1048576;       // ks=1 partial at +4*512*2048 floats
  f32x4 v[8];
  float s = 0.f, ss = 0.f;
#pragma unroll
  for (int k = 0; k < 8; ++k) {
    int f = tid + k * 1024;             // [0,8192) f4 within group
    f32x4 a = a4[f], c = c4[f];
#pragma unroll
    for (int e = 0; e < 4; ++e) {
      float x = a[e] + c[e];
      v[k][e] = x;
      s += x; ss += x * x;
    }
  }
#pragma unroll
  for (int off = 32; off > 0; off >>= 1) {
    s  += __shfl_xor(s, off);
    ss += __shfl_xor(ss, off);
  }
  __shared__ float w1[16], w2[16];
  __shared__ float stat[2];
  int wave = tid >> 6, lane = tid & 63;
  if (lane == 0) { w1[wave] = s; w2[wave] = ss; }
  __syncthreads();
  if (tid == 0) {
    float t1 = 0.f, t2 = 0.f;
    for (int i = 0; i < 16; ++i) { t1 += w1[i]; t2 += w2[i]; }
    float mu = t1 * (1.f / 32768.f);
    stat[0] = mu;
    stat[1] = 1.0f / sqrtf(t2 * (1.f / 32768.f) - mu * mu + 1e-5f);
  }
  __syncthreads();
  const float mu = stat[0], rs = stat[1];
  f32x4* o4 = (f32x4*)(out + ((size_t)b * 512 + g * 16) * 2048);
#pragma unroll
  for (int k = 0; k < 8; ++k) {
    int f = tid + k * 1024;
    int ch = g * 16 + (f >> 9);         // 512 f4 per channel row
    float ga = gamma[ch], bt = beta[ch];
    f32x4 o;
#pragma unroll
    for (int e = 0; e < 4; ++e)
      o[e] = relu((v[k][e] - mu) * rs * ga + bt);
    o4[f] = o;
  }
}

// ---------------------------------------------------------------------------
extern "C" void kernel_launch(void* const* d_in, const int* in_sizes, int n_in,
                              void* d_out, int out_size, void* d_ws, size_t ws_size,
                              hipStream_t stream) {
  const float* feature = (const float*)d_in[0];
  const float* frame   = (const float*)d_in[1];
  const float* W1 = (const float*)d_in[2];
  const float* b1 = (const float*)d_in[3];
  const float* g1 = (const float*)d_in[4];
  const float* be1 = (const float*)d_in[5];
  const float* W2 = (const float*)d_in[6];
  const float* b2 = (const float*)d_in[7];
  const float* g2 = (const float*)d_in[8];
  const float* be2 = (const float*)d_in[9];
  const float* W3 = (const float*)d_in[10];
  const float* b3 = (const float*)d_in[11];
  const float* g3 = (const float*)d_in[12];
  const float* be3 = (const float*)d_in[13];

  char* ws = (char*)d_ws;
  // Layout / stream-ordered aliasing:
  //   X3T   [0, 32MiB)            bf16 (B,2048t,2048c)
  //   Y12f  [32MiB, 80MiB)        f32 (B,1536,2048) = GEMM1+2 output
  //   Y3p   [32MiB, 64MiB)        f32 split-K partial pair (after normT12)
  //   partD [48MiB, +256KiB)      f64, dead before gemm12 writes Y12
  //   featT [80MiB, 88MiB)        bf16 (B,2048,512); W3b aliases it after
  //                               gemm12 (featT dead; normT12 writes W3b)
  //   W12b  [88MiB, +1.5MiB)      bf16 stacked W1;W2
  //   small tail after W12b (cdf/raw1/raw2)
  u16*    X3T   = (u16*)(ws + 0);
  float*  Y12f  = (float*)(ws + 33554432);
  float*  Y3p   = (float*)(ws + 33554432);
  double* partD = (double*)(ws + 50331648);
  u16*    featT = (u16*)(ws + 83886080);
  u16*    W3b   = (u16*)(ws + 83886080);   // aliases dead featT
  u16*    W12b  = (u16*)(ws + 92274688);
  int*    cdf   = (int*)(ws + 93847552);
  float*  raw1  = (float*)(ws + 93872128);
  float*  raw2  = (float*)(ws + 93873152);

  float* outMixed = (float*)d_out;                       // (B,512,2048) fp32
  float* outFeat  = outMixed + (size_t)4 * 512 * 2048;   // (B,1024,2048) fp32

  colmean_part_kernel<<<dim3(16, 8), 256, 0, stream>>>(frame, partD, raw1);
  scanD_kernel<<<1, 256, 0, stream>>>(partD, cdf);
  gatherTrans_kernel<<<dim3(8, 32, 11), 256, 0, stream>>>(frame, feature, cdf,
                                                          W1, W2, X3T, featT, W12b);
  gemm12_kernel<<<dim3(16, 24, 4), 128, 0, stream>>>(W12b, featT, b1, b2, Y12f,
                                                     raw1, raw2);
  normT12_kernel<<<dim3(32, 25, 4), 256, 0, stream>>>(Y12f, raw1, raw2,
                                                      g1, be1, g2, be2,
                                                      W3, W3b, X3T, outFeat);
  gemm3s_kernel<<<dim3(16, 8, 8), 128, 0, stream>>>(W3b, X3T, b3, Y3p);
  norm3g_kernel<<<dim3(32, 4), 1024, 0, stream>>>(Y3p, g3, be3, outMixed);
}

// Round 14
// 255.266 us; speedup vs baseline: 1.4210x; 1.0108x over previous
//
#include <hip/hip_runtime.h>

typedef unsigned short u16;
typedef unsigned int   u32;
typedef __attribute__((ext_vector_type(8))) short short8;
typedef __attribute__((ext_vector_type(4))) short short4_t;
typedef __attribute__((ext_vector_type(4))) float f32x4;

__device__ __forceinline__ float bf2f(u16 v) {
  return __uint_as_float(((u32)v) << 16);
}
__device__ __forceinline__ u16 f2bf(float f) {
  u32 u = __float_as_uint(f);
  u32 r = (u + 0x7FFFu + ((u >> 16) & 1u)) >> 16;   // RNE
  return (u16)r;
}
// NaN-propagating ReLU (fmaxf(NaN,0)=0 would hide poison as zeros)
__device__ __forceinline__ float relu(float x) { return x < 0.f ? 0.f : x; }

// async global->LDS, 16B/lane; LDS dest = wave-uniform base + lane*16
__device__ __forceinline__ void gld16(const void* g, void* l) {
  __builtin_amdgcn_global_load_lds((const __attribute__((address_space(1))) u32*)g,
                                   (__attribute__((address_space(3))) u32*)l, 16, 0, 0);
}

// ---------------------------------------------------------------------------
// 1a. partial column sums of frame batch 0; block (0,0) also zeroes
//     raw1/raw2 (512 floats) — replaces hipMemsetAsync.
__global__ void colmean_part_kernel(const float* __restrict__ frame,
                                    double* __restrict__ partD,
                                    float* __restrict__ rawZ) {
  if (blockIdx.x == 0 && blockIdx.y == 0) {
    rawZ[threadIdx.x] = 0.f;
    rawZ[threadIdx.x + 256] = 0.f;
  }
  int tf = blockIdx.x * 256 + threadIdx.x;           // 4096
  int ch = blockIdx.y;                               // 8 chunks
  const float* f0 = frame + tf + (size_t)ch * 64 * 4096;
  double s = 0.0;
  for (int c = 0; c < 64; ++c) s += (double)f0[(size_t)c * 4096];
  partD[ch * 4096 + tf] = s;
}

// ---------------------------------------------------------------------------
// 2. f64: mean = (in-order chunk combine)/512; S = sum; q = mean/S; cumsum;
//    cdf = min(int(c*2048), 2047).  (Ordering kept exactly as verified —
//    reordering f64 sums risks a 1-ULP cdf flip -> different gather idx.)
__global__ void scanD_kernel(const double* __restrict__ partD, int* __restrict__ cdf) {
  __shared__ double part[256];
  __shared__ double base[256];
  __shared__ double Ss;
  int tid = threadIdx.x;
  double loc[16];
  double s = 0.0;
#pragma unroll
  for (int i = 0; i < 16; ++i) {
    int tf = tid * 16 + i;
    double m = 0.0;
#pragma unroll
    for (int ch = 0; ch < 8; ++ch) m += partD[ch * 4096 + tf];  // in c-order
    loc[i] = m / 512.0;
    s += loc[i];
  }
  part[tid] = s;
  __syncthreads();
  if (tid == 0) {
    double t = 0.0;
    for (int i = 0; i < 256; ++i) t += part[i];
    Ss = t;
  }
  __syncthreads();
  double S = Ss;
  s = 0.0;
#pragma unroll
  for (int i = 0; i < 16; ++i) { loc[i] = loc[i] / S; s += loc[i]; }
  part[tid] = s;
  __syncthreads();
  if (tid == 0) {
    double c = 0.0;
    for (int i = 0; i < 256; ++i) { base[i] = c; c += part[i]; }
  }
  __syncthreads();
  double c = base[tid];
#pragma unroll
  for (int i = 0; i < 16; ++i) {
    c += loc[i];
    int iv = (int)(c * 2048.0);                      // trunc = astype(int32)
    cdf[tid * 16 + i] = iv < 2047 ? iv : 2047;
  }
}

// ---------------------------------------------------------------------------
// first argmin_j |cdf[j]-t| for MONOTONE non-decreasing cdf (r11-verified).
__device__ __forceinline__ int lowbound(const int* __restrict__ cdf, int hi0, int v) {
  int lo = 0, hi = hi0;
  while (lo < hi) { int mid = (lo + hi) >> 1; if (cdf[mid] < v) lo = mid + 1; else hi = mid; }
  return lo;
}
__device__ __forceinline__ int argmin_cdf(const int* __restrict__ cdf, int t) {
  int j2 = lowbound(cdf, 4096, t);       // first index with cdf >= t
  if (j2 == 0) return 0;                 // plateau head of v2 is j2 itself
  if (j2 == 4096) return lowbound(cdf, 4096, cdf[4095]);
  int d2 = cdf[j2] - t, d1 = t - cdf[j2 - 1];
  if (d2 < d1) return j2;                // j2 is first index with value v2
  return lowbound(cdf, j2, cdf[j2 - 1]); // head of v1 plateau (d1<=d2 -> earlier)
}

// ---------------------------------------------------------------------------
// 4+5+6a merged (r10/r11-verified) + inline argmin.
//   z<4: gather X3T; z<8: transpose featT; z>=8: convW12
__global__ void gatherTrans_kernel(const float* __restrict__ frame,
                                   const float* __restrict__ feature,
                                   const int* __restrict__ cdf,
                                   const float* __restrict__ W1,
                                   const float* __restrict__ W2,
                                   u16* __restrict__ X3T, u16* __restrict__ featT,
                                   u16* __restrict__ W12b) {
  __shared__ u16 tile[64][65];
  __shared__ int sidx[64];
  int tid = threadIdx.x;
  int zz = blockIdx.z;
  if (zz >= 8) {                        // weight conversion slice
    int flat = (zz - 8) * 256 + blockIdx.y * 8 + blockIdx.x;   // [0,768)
    int i = (flat * 256 + tid) * 4;
    f32x4 v = *(const f32x4*)(i < 262144 ? W1 + i : W2 + (i - 262144));
    short4_t o;
#pragma unroll
    for (int e = 0; e < 4; ++e) o[e] = (short)f2bf(v[e]);
    *(short4_t*)(W12b + i) = o;
    return;
  }
  int cb = blockIdx.x * 64, t0 = blockIdx.y * 64;
  int b = zz & 3, which = zz >> 2;
  if (which == 0) {
    if (tid < 64) sidx[tid] = argmin_cdf(cdf, t0 + tid);   // in [0,4095]
    __syncthreads();
    const float* fb = frame + (size_t)b * 512 * 4096;
    for (int i = tid; i < 4096; i += 256) {
      int r = i >> 6, tt = i & 63;        // r = c-local, tt = t-local
      tile[tt][r] = f2bf(fb[(size_t)(cb + r) * 4096 + sidx[tt]]);
    }
    __syncthreads();
    u16* xb = X3T + (size_t)b * 2048 * 2048;
    for (int i = tid; i < 4096; i += 256) {
      int r = i >> 6, cc = i & 63;        // r = t-local, cc = c-local
      xb[(size_t)(t0 + r) * 2048 + cb + cc] = tile[r][cc];
    }
  } else {
    const float* xb = feature + (size_t)b * 512 * 2048;
    for (int i = tid; i < 4096; i += 256) {
      int r = i >> 6, tt = i & 63;        // coalesced along t
      tile[tt][r] = f2bf(xb[(size_t)(cb + r) * 2048 + t0 + tt]);
    }
    __syncthreads();
    u16* xtb = featT + (size_t)b * 2048 * 512;
    for (int i = tid; i < 4096; i += 256) {
      int r = i >> 6, cc = i & 63;
      xtb[(size_t)(t0 + r) * 512 + cb + cc] = tile[r][cc];
    }
  }
}

// ---------------------------------------------------------------------------
// 7a. fused GEMM1+2 (r2/r7/r8-verified): Y12 + bias; GN1/GN2 stats fused.
//     M=1536, N=2048, K=512. 64x128 tile, 2 waves. Conflict-free both-sides
//     16B-slot XOR swizzle. 1536 blocks -> 6/CU resident.
//     r13: Y12 stored BF16 (24MB vs 48MB). Stats stay exact f32 in-register;
//     normalize reads rounded values -> added error ~0.002|v-mu|/sigma, well
//     inside the 0.11 threshold (was 0.03125).
__global__ __launch_bounds__(128) void gemm12_kernel(
    const u16* __restrict__ A, const u16* __restrict__ Bt,
    const float* __restrict__ b1, const float* __restrict__ b2,
    u16* __restrict__ Y, float* __restrict__ raw1, float* __restrict__ raw2)
{
  const int K = 512;
  __shared__ short As[2][2048];   // [buf][64 m][32 k]
  __shared__ short Bs[2][4096];   // [buf][128 n][32 k]
  const int tid = threadIdx.x;
  const int lane = tid & 63;
  const int w = tid >> 6;
  const int nt = blockIdx.x, mt = blockIdx.y, bb = blockIdx.z;
  const u16* Ab = A + (size_t)mt * 64 * K;
  const u16* Bb = Bt + ((size_t)bb * 2048 + (size_t)nt * 128) * K;
  const int lm = lane & 15, lq = lane >> 4;
  f32x4 acc[4][4] = {};

  auto stage = [&](int buf, int kt) {
#pragma unroll
    for (int p = 0; p < 2; ++p) {
      int chunk = tid + 128 * p;
      int row = chunk >> 2;
      int ko = ((chunk & 3) ^ ((row >> 1) & 3)) << 3;   // source pre-swizzle
      gld16(Ab + (size_t)row * K + kt + ko, (char*)As[buf] + chunk * 16);
    }
#pragma unroll
    for (int p = 0; p < 4; ++p) {
      int chunk = tid + 128 * p;
      int row = chunk >> 2;
      int ko = ((chunk & 3) ^ ((row >> 1) & 3)) << 3;
      gld16(Bb + (size_t)row * K + kt + ko, (char*)Bs[buf] + chunk * 16);
    }
  };

  stage(0, 0);
  for (int s = 0; s < 16; ++s) {
    int cur = s & 1;
    __syncthreads();
    if (s + 1 < 16) stage(cur ^ 1, (s + 1) << 5);
    short8 af[4], bfv[4];
#pragma unroll
    for (int i = 0; i < 4; ++i) {
      int r = i * 16 + lm;
      af[i] = *(const short8*)(As[cur] + r * 32 + ((lq ^ ((r >> 1) & 3)) << 3));
    }
#pragma unroll
    for (int j = 0; j < 4; ++j) {
      int r = w * 64 + j * 16 + lm;
      bfv[j] = *(const short8*)(Bs[cur] + r * 32 + ((lq ^ ((r >> 1) & 3)) << 3));
    }
#pragma unroll
    for (int i = 0; i < 4; ++i)
#pragma unroll
      for (int j = 0; j < 4; ++j)
        acc[i][j] = __builtin_amdgcn_mfma_f32_16x16x32_bf16(af[i], bfv[j], acc[i][j], 0, 0, 0);
  }

  float s1[4] = {0.f, 0.f, 0.f, 0.f};
  float s2[4] = {0.f, 0.f, 0.f, 0.f};
#pragma unroll
  for (int i = 0; i < 4; ++i) {
    int mbase = mt * 64 + i * 16 + lq * 4;
#pragma unroll
    for (int e = 0; e < 4; ++e) {
      int m = mbase + e;
      float bv = m < 512 ? b1[m] : b2[m - 512];
      u16* yp = Y + ((size_t)bb * 1536 + m) * 2048 + nt * 128 + w * 64 + lm;
#pragma unroll
      for (int j = 0; j < 4; ++j) {
        float v = acc[i][j][e] + bv;
        yp[j * 16] = f2bf(v);
        s1[i] += v; s2[i] += v * v;
      }
    }
  }
#pragma unroll
  for (int i = 0; i < 4; ++i) {
#pragma unroll
    for (int off = 32; off > 0; off >>= 1) {
      s1[i] += __shfl_xor(s1[i], off);
      s2[i] += __shfl_xor(s2[i], off);
    }
  }
  if (lane == 0) {
    if (mt < 8) {                                  // GN1: cpg=16, frag = 1 group
#pragma unroll
      for (int i = 0; i < 4; ++i) {
        int g = mt * 4 + i;
        atomicAdd(&raw1[(bb * 32 + g) * 2],     s1[i]);
        atomicAdd(&raw1[(bb * 32 + g) * 2 + 1], s2[i]);
      }
    } else {                                       // GN2: cpg=32, 2 frags = 1 group
#pragma unroll
      for (int i = 0; i < 2; ++i) {
        int g = (mt - 8) * 2 + i;
        atomicAdd(&raw2[(bb * 32 + g) * 2],     s1[2 * i] + s1[2 * i + 1]);
        atomicAdd(&raw2[(bb * 32 + g) * 2 + 1], s2[2 * i] + s2[2 * i + 1]);
      }
    }
  }
}

// ---------------------------------------------------------------------------
// 7b. GEMM3 split-K x2 (r2/r7/r8-verified). M=512, N=2048, K=2048. 64x128
//     tile, 2 waves, grid.z = b*2+ks -> 1024 blocks. Conflict-free swizzle.
//     r13: partials stored BF16 (17MB vs 33MB). Sum of two rounded partials
//     adds ~0.006*sigma pre-GN error -> ~0.02 normalized; margin holds.
__global__ __launch_bounds__(128) void gemm3s_kernel(
    const u16* __restrict__ A, const u16* __restrict__ Bt,
    const float* __restrict__ bias, u16* __restrict__ Yp)
{
  const int K = 2048;
  __shared__ short As[2][2048];
  __shared__ short Bs[2][4096];
  const int tid = threadIdx.x;
  const int lane = tid & 63;
  const int w = tid >> 6;
  const int nt = blockIdx.x, mt = blockIdx.y;
  const int bb = blockIdx.z >> 1, ks = blockIdx.z & 1;
  const u16* Ab = A + (size_t)mt * 64 * K + ks * 1024;
  const u16* Bb = Bt + ((size_t)bb * 2048 + (size_t)nt * 128) * K + ks * 1024;
  const int lm = lane & 15, lq = lane >> 4;
  f32x4 acc[4][4] = {};

  auto stage = [&](int buf, int kt) {
#pragma unroll
    for (int p = 0; p < 2; ++p) {
      int chunk = tid + 128 * p;
      int row = chunk >> 2;
      int ko = ((chunk & 3) ^ ((row >> 1) & 3)) << 3;
      gld16(Ab + (size_t)row * K + kt + ko, (char*)As[buf] + chunk * 16);
    }
#pragma unroll
    for (int p = 0; p < 4; ++p) {
      int chunk = tid + 128 * p;
      int row = chunk >> 2;
      int ko = ((chunk & 3) ^ ((row >> 1) & 3)) << 3;
      gld16(Bb + (size_t)row * K + kt + ko, (char*)Bs[buf] + chunk * 16);
    }
  };

  stage(0, 0);
  for (int s = 0; s < 32; ++s) {
    int cur = s & 1;
    __syncthreads();
    if (s + 1 < 32) stage(cur ^ 1, (s + 1) << 5);
    short8 af[4], bfv[4];
#pragma unroll
    for (int i = 0; i < 4; ++i) {
      int r = i * 16 + lm;
      af[i] = *(const short8*)(As[cur] + r * 32 + ((lq ^ ((r >> 1) & 3)) << 3));
    }
#pragma unroll
    for (int j = 0; j < 4; ++j) {
      int r = w * 64 + j * 16 + lm;
      bfv[j] = *(const short8*)(Bs[cur] + r * 32 + ((lq ^ ((r >> 1) & 3)) << 3));
    }
#pragma unroll
    for (int i = 0; i < 4; ++i)
#pragma unroll
      for (int j = 0; j < 4; ++j)
        acc[i][j] = __builtin_amdgcn_mfma_f32_16x16x32_bf16(af[i], bfv[j], acc[i][j], 0, 0, 0);
  }
#pragma unroll
  for (int i = 0; i < 4; ++i) {
    int mbase = mt * 64 + i * 16 + lq * 4;
#pragma unroll
    for (int e = 0; e < 4; ++e) {
      int m = mbase + e;
      float bv = ks ? 0.f : bias[m];
      u16* yp = Yp + ((size_t)(ks * 4 + bb) * 512 + m) * 2048 + nt * 128 + w * 64 + lm;
#pragma unroll
      for (int j = 0; j < 4; ++j)
        yp[j * 16] = f2bf(acc[i][j][e] + bv);
    }
  }
}

// ---------------------------------------------------------------------------
// 9. normT1+normT2 merged (r8-verified) + convW(W3) folded as y==24 slice.
//    r13: reads BF16 Y12 (half the FETCH).
__global__ void normT12_kernel(const u16* __restrict__ Y,
                               const float* __restrict__ raw1,
                               const float* __restrict__ raw2,
                               const float* __restrict__ g1, const float* __restrict__ be1,
                               const float* __restrict__ g2, const float* __restrict__ be2,
                               const float* __restrict__ W3, u16* __restrict__ W3b,
                               u16* __restrict__ X3T, float* __restrict__ featOut) {
  __shared__ u16 tile[64][65];           // [t_local][c_local]
  int b = blockIdx.z, t0 = blockIdx.x * 64;
  int yb_idx = blockIdx.y;
  if (yb_idx == 24) {                    // W3 -> bf16 slice: 128 blocks
    int flat = blockIdx.z * 32 + blockIdx.x;            // [0,128)
#pragma unroll
    for (int k = 0; k < 8; ++k) {
      int i = (flat * 2048 + k * 256 + threadIdx.x) * 4;  // 1048576 u16 total
      f32x4 v = *(const f32x4*)(W3 + i);
      short4_t o;
#pragma unroll
      for (int e = 0; e < 4; ++e) o[e] = (short)f2bf(v[e]);
      *(short4_t*)(W3b + i) = o;
    }
    return;
  }
  const int gn2 = yb_idx >= 8;
  int c0 = (gn2 ? yb_idx - 8 : yb_idx) * 64;
  const float* raw   = gn2 ? raw2 : raw1;
  const float* gamma = gn2 ? g2 : g1;
  const float* beta  = gn2 ? be2 : be1;
  const float inv_n  = gn2 ? (1.f / 65536.f) : (1.f / 32768.f);
  const int chBase   = gn2 ? 512 : 0;
  const int gShift   = gn2 ? 5 : 4;
  const int colBase  = gn2 ? 512 : 1536;
  const u16* yb = Y + ((size_t)b * 1536 + chBase) * 2048;
  for (int i = threadIdx.x; i < 4096; i += 256) {
    int r = i >> 6, cc = i & 63;         // r: channel-local, cc: t-local
    int ch = c0 + r;
    int gI = (b * 32 + (ch >> gShift)) * 2;
    float mu = raw[gI] * inv_n;
    float var = raw[gI + 1] * inv_n - mu * mu;
    float rs = 1.0f / sqrtf(var + 1e-5f);
    float v = bf2f(yb[(size_t)ch * 2048 + t0 + cc]);
    float o = relu((v - mu) * rs * gamma[ch] + beta[ch]);
    tile[cc][r] = f2bf(o);
    if (gn2) featOut[((size_t)b * 1024 + ch) * 2048 + t0 + cc] = o;
  }
  __syncthreads();
  for (int i = threadIdx.x; i < 4096; i += 256) {
    int r = i >> 6, cc = i & 63;         // r: t-local, cc: c-local
    X3T[((size_t)b * 2048 + t0 + r) * 2048 + colBase + c0 + cc] = tile[r][cc];
  }
}

// ---------------------------------------------------------------------------
// 10. MERGED stats+GN+ReLU for split-K Y3 (r12-verified structure).
//     r13: reads BF16 partial pair via short8 (16B/lane). One block per
//     (batch, group); values live in registers across the stats reduce.
__global__ __launch_bounds__(1024) void norm3g_kernel(
    const u16* __restrict__ Yp,
    const float* __restrict__ gamma, const float* __restrict__ beta,
    float* __restrict__ out)
{
  const int tid = threadIdx.x;          // 1024
  const int g = blockIdx.x;             // 32 groups
  const int b = blockIdx.y;             // 4 batches
  const short8* a8 = (const short8*)(Yp + ((size_t)b * 512 + g * 16) * 2048);
  const short8* c8 = a8 + 524288;       // ks=1 partial at +4*512*2048 u16
  float v[4][8];
  float s = 0.f, ss = 0.f;
#pragma unroll
  for (int k = 0; k < 4; ++k) {
    int f = tid + k * 1024;             // [0,4096) short8 within group
    short8 a = a8[f], c = c8[f];
#pragma unroll
    for (int e = 0; e < 8; ++e) {
      float x = bf2f((u16)a[e]) + bf2f((u16)c[e]);
      v[k][e] = x;
      s += x; ss += x * x;
    }
  }
#pragma unroll
  for (int off = 32; off > 0; off >>= 1) {
    s  += __shfl_xor(s, off);
    ss += __shfl_xor(ss, off);
  }
  __shared__ float w1[16], w2[16];
  __shared__ float stat[2];
  int wave = tid >> 6, lane = tid & 63;
  if (lane == 0) { w1[wave] = s; w2[wave] = ss; }
  __syncthreads();
  if (tid == 0) {
    float t1 = 0.f, t2 = 0.f;
    for (int i = 0; i < 16; ++i) { t1 += w1[i]; t2 += w2[i]; }
    float mu = t1 * (1.f / 32768.f);
    stat[0] = mu;
    stat[1] = 1.0f / sqrtf(t2 * (1.f / 32768.f) - mu * mu + 1e-5f);
  }
  __syncthreads();
  const float mu = stat[0], rs = stat[1];
  f32x4* orow = (f32x4*)(out + ((size_t)b * 512 + g * 16) * 2048);
#pragma unroll
  for (int k = 0; k < 4; ++k) {
    int f = tid + k * 1024;
    int ch = g * 16 + (f >> 8);         // 256 short8 per channel row
    float ga = gamma[ch], bt = beta[ch];
    f32x4 o0, o1;
#pragma unroll
    for (int e = 0; e < 4; ++e) {
      o0[e] = relu((v[k][e]     - mu) * rs * ga + bt);
      o1[e] = relu((v[k][4 + e] - mu) * rs * ga + bt);
    }
    orow[f * 2]     = o0;
    orow[f * 2 + 1] = o1;
  }
}

// ---------------------------------------------------------------------------
extern "C" void kernel_launch(void* const* d_in, const int* in_sizes, int n_in,
                              void* d_out, int out_size, void* d_ws, size_t ws_size,
                              hipStream_t stream) {
  const float* feature = (const float*)d_in[0];
  const float* frame   = (const float*)d_in[1];
  const float* W1 = (const float*)d_in[2];
  const float* b1 = (const float*)d_in[3];
  const float* g1 = (const float*)d_in[4];
  const float* be1 = (const float*)d_in[5];
  const float* W2 = (const float*)d_in[6];
  const float* b2 = (const float*)d_in[7];
  const float* g2 = (const float*)d_in[8];
  const float* be2 = (const float*)d_in[9];
  const float* W3 = (const float*)d_in[10];
  const float* b3 = (const float*)d_in[11];
  const float* g3 = (const float*)d_in[12];
  const float* be3 = (const float*)d_in[13];

  char* ws = (char*)d_ws;
  // Layout / stream-ordered aliasing (r13: bf16 intermediates):
  //   X3T   [0, 32MiB)            bf16 (B,2048t,2048c)
  //   Y12b  [32MiB, 56MiB)        bf16 (B,1536,2048) = GEMM1+2 output
  //   Y3p   [32MiB, 48MiB)        bf16 split-K partial pair (after normT12;
  //                               aliases dead Y12b — stream-ordered)
  //   partD [48MiB, +256KiB)      f64, dead before gemm3s writes near it
  //   featT [80MiB, 88MiB)        bf16 (B,2048,512); W3b aliases it after
  //                               gemm12 (featT dead; normT12 writes W3b)
  //   W12b  [88MiB, +1.5MiB)      bf16 stacked W1;W2
  //   small tail after W12b (cdf/raw1/raw2)
  u16*    X3T   = (u16*)(ws + 0);
  u16*    Y12b  = (u16*)(ws + 33554432);
  u16*    Y3p   = (u16*)(ws + 33554432);   // aliases dead Y12b
  double* partD = (double*)(ws + 50331648);
  u16*    featT = (u16*)(ws + 83886080);
  u16*    W3b   = (u16*)(ws + 83886080);   // aliases dead featT
  u16*    W12b  = (u16*)(ws + 92274688);
  int*    cdf   = (int*)(ws + 93847552);
  float*  raw1  = (float*)(ws + 93872128);
  float*  raw2  = (float*)(ws + 93873152);

  float* outMixed = (float*)d_out;                       // (B,512,2048) fp32
  float* outFeat  = outMixed + (size_t)4 * 512 * 2048;   // (B,1024,2048) fp32

  colmean_part_kernel<<<dim3(16, 8), 256, 0, stream>>>(frame, partD, raw1);
  scanD_kernel<<<1, 256, 0, stream>>>(partD, cdf);
  gatherTrans_kernel<<<dim3(8, 32, 11), 256, 0, stream>>>(frame, feature, cdf,
                                                          W1, W2, X3T, featT, W12b);
  gemm12_kernel<<<dim3(16, 24, 4), 128, 0, stream>>>(W12b, featT, b1, b2, Y12b,
                                                     raw1, raw2);
  normT12_kernel<<<dim3(32, 25, 4), 256, 0, stream>>>(Y12b, raw1, raw2,
                                                      g1, be1, g2, be2,
                                                      W3, W3b, X3T, outFeat);
  gemm3s_kernel<<<dim3(16, 8, 8), 128, 0, stream>>>(W3b, X3T, b3, Y3p);
  norm3g_kernel<<<dim3(32, 4), 1024, 0, stream>>>(Y3p, g3, be3, outMixed);
}